// Round 2
// baseline (395.156 us; speedup 1.0000x reference)
//
#include <hip/hip_runtime.h>
#include <stdint.h>

#define NTOK   16384      // B*T = 4*4096
#define DM     1024
#define DI     512
#define NH     8
#define DH     64
#define CHUNK  64
#define NCH    64         // T / CHUNK
#define NBHC   2048       // B*H*NCH

using short8 = __attribute__((ext_vector_type(8))) short;
using f32x4  = __attribute__((ext_vector_type(4))) float;

__device__ __forceinline__ unsigned short f2bf(float f) {
  union { float f; unsigned int u; } x; x.f = f;
  unsigned int u = x.u;
  return (unsigned short)((u + 0x7fffu + ((u >> 16) & 1u)) >> 16);
}
__device__ __forceinline__ float bf2f(unsigned short h) {
  union { unsigned int u; float f; } x; x.u = ((unsigned int)h) << 16; return x.f;
}

typedef const __attribute__((address_space(1))) void* gp1_t;
typedef __attribute__((address_space(3))) void* lp3_t;
__device__ __forceinline__ void gload_lds16(const void* g, void* l) {
  __builtin_amdgcn_global_load_lds((gp1_t)g, (lp3_t)l, 16, 0, 0);
}

// ---------------- K0: fp32 -> bf16 transpose (out[n][k] = in[k][n]) ----------
__global__ __launch_bounds__(256) void transpose_bf16(const float* __restrict__ in,
                                                      unsigned short* __restrict__ out,
                                                      int R, int C) {
  __shared__ float tile[32][33];
  int bx = blockIdx.x * 32;           // col base (output row base)
  int by = blockIdx.y * 32;           // row base
  int tx = threadIdx.x & 31, ty = threadIdx.x >> 5;
  #pragma unroll
  for (int r = ty; r < 32; r += 8) tile[r][tx] = in[(long)(by + r) * C + bx + tx];
  __syncthreads();
  #pragma unroll
  for (int r = ty; r < 32; r += 8) out[(long)(bx + r) * R + by + tx] = f2bf(tile[tx][r]);
}

// ---------------- K1: LayerNorm -> bf16 --------------------------------------
__global__ __launch_bounds__(256) void ln_kernel(const float* __restrict__ x,
                                                 const float* __restrict__ gamma,
                                                 const float* __restrict__ beta,
                                                 unsigned short* __restrict__ xn) {
  const int row = blockIdx.x, tid = threadIdx.x;
  float4 v = ((const float4*)(x + (long)row * DM))[tid];
  float s  = v.x + v.y + v.z + v.w;
  float ss = v.x * v.x + v.y * v.y + v.z * v.z + v.w * v.w;
  #pragma unroll
  for (int off = 32; off > 0; off >>= 1) { s += __shfl_down(s, off); ss += __shfl_down(ss, off); }
  __shared__ float rs_[4], rss_[4];
  int wave = tid >> 6, lane = tid & 63;
  if (lane == 0) { rs_[wave] = s; rss_[wave] = ss; }
  __syncthreads();
  s  = rs_[0] + rs_[1] + rs_[2] + rs_[3];
  ss = rss_[0] + rss_[1] + rss_[2] + rss_[3];
  float mu   = s * (1.f / DM);
  float var  = ss * (1.f / DM) - mu * mu;
  float rstd = rsqrtf(var + 1e-5f);
  int idx = tid * 4;
  float xv[4] = {v.x, v.y, v.z, v.w};
  unsigned short o[4];
  #pragma unroll
  for (int j = 0; j < 4; ++j) o[j] = f2bf((xv[j] - mu) * rstd * gamma[idx + j] + beta[idx + j]);
  uint2 pk; pk.x = (unsigned)o[0] | ((unsigned)o[1] << 16); pk.y = (unsigned)o[2] | ((unsigned)o[3] << 16);
  *(uint2*)(xn + (long)row * DM + idx) = pk;
}

// ---------------- GEMM: C[M][N] = A(bf16 MxK) * Bt(bf16 NxK)^T ---------------
// MODE 0: store bf16 to Cb.  MODE 1: store fp32 + residual to Cf.
template <int MODE>
__global__ __launch_bounds__(256) void gemm_bt(const unsigned short* __restrict__ A,
                                               const unsigned short* __restrict__ Bt,
                                               unsigned short* __restrict__ Cb,
                                               float* __restrict__ Cf,
                                               const float* __restrict__ resid,
                                               int M, int N, int K) {
  __shared__ __align__(16) unsigned short As[128 * 32];
  __shared__ __align__(16) unsigned short Bs[128 * 32];
  const int tid = threadIdx.x;
  const int wave = tid >> 6, lane = tid & 63;
  const int quad = lane >> 4, l16 = lane & 15;
  const int m0 = blockIdx.x * 128, n0 = blockIdx.y * 128;
  const int wm = (wave & 1) * 64, wn = (wave >> 1) * 64;

  const int c0 = tid, c1 = tid + 256;
  const unsigned short* Ag0 = A + (long)(m0 + (c0 >> 2)) * K + (c0 & 3) * 8;
  const unsigned short* Ag1 = A + (long)(m0 + (c1 >> 2)) * K + (c1 & 3) * 8;
  const unsigned short* Bg0 = Bt + (long)(n0 + (c0 >> 2)) * K + (c0 & 3) * 8;
  const unsigned short* Bg1 = Bt + (long)(n0 + (c1 >> 2)) * K + (c1 & 3) * 8;

  f32x4 acc[4][4];
  #pragma unroll
  for (int i = 0; i < 4; ++i)
    #pragma unroll
    for (int j = 0; j < 4; ++j) acc[i][j] = (f32x4){0.f, 0.f, 0.f, 0.f};

  for (int k0 = 0; k0 < K; k0 += 32) {
    __syncthreads();
    gload_lds16(Ag0 + k0, &As[c0 * 8]);
    gload_lds16(Ag1 + k0, &As[c1 * 8]);
    gload_lds16(Bg0 + k0, &Bs[c0 * 8]);
    gload_lds16(Bg1 + k0, &Bs[c1 * 8]);
    __syncthreads();
    short8 a[4], b[4];
    #pragma unroll
    for (int mt = 0; mt < 4; ++mt) a[mt] = *(const short8*)&As[(wm + mt * 16 + l16) * 32 + quad * 8];
    #pragma unroll
    for (int nt = 0; nt < 4; ++nt) b[nt] = *(const short8*)&Bs[(wn + nt * 16 + l16) * 32 + quad * 8];
    #pragma unroll
    for (int mt = 0; mt < 4; ++mt)
      #pragma unroll
      for (int nt = 0; nt < 4; ++nt)
        acc[mt][nt] = __builtin_amdgcn_mfma_f32_16x16x32_bf16(a[mt], b[nt], acc[mt][nt], 0, 0, 0);
  }
  #pragma unroll
  for (int mt = 0; mt < 4; ++mt)
    #pragma unroll
    for (int nt = 0; nt < 4; ++nt)
      #pragma unroll
      for (int r = 0; r < 4; ++r) {
        int row = m0 + wm + mt * 16 + quad * 4 + r;
        int col = n0 + wn + nt * 16 + l16;
        float v = acc[mt][nt][r];
        if (MODE == 0) {
          Cb[(long)row * N + col] = f2bf(v);
        } else {
          Cf[(long)row * N + col] = v + resid[(long)row * N + col];
        }
      }
}

// ---------------- K3: per-chunk prep (sigmoid, cumprod, k-norm, rescale) -----
// Cb row layout (bf16): [q 0..511 | k 512..1023 | v 1024..1535 | alog 1536..2047]
__global__ __launch_bounds__(64) void prep_kernel(const unsigned short* __restrict__ Cb,
                                                  const float* __restrict__ ba,
                                                  unsigned short* __restrict__ qt,
                                                  unsigned short* __restrict__ kt,
                                                  unsigned short* __restrict__ khat,
                                                  unsigned short* __restrict__ vtb,
                                                  float* __restrict__ Dvec) {
  const int bhc = blockIdx.x;
  const int c = bhc & 63, bh = bhc >> 6;
  const int h = bh & 7, b = bh >> 3;
  const int d = threadIdx.x;
  __shared__ float kL[64 * 65];
  __shared__ float lamL[64 * 64];
  __shared__ float rn[64];
  const long rowbase = ((long)(b * 4096 + c * 64)) * 2048;
  const int off = h * 64 + d;
  const float bav = ba[off];
  float cum = 1.f;
  for (int t = 0; t < 64; ++t) {
    long g = rowbase + (long)t * 2048;
    float z = bf2f(Cb[g + 1536 + off]) + bav;
    float a = 1.f / (1.f + expf(-z));
    cum *= a;
    lamL[t * 64 + d] = cum;
    kL[t * 65 + d] = bf2f(Cb[g + 512 + off]);
  }
  Dvec[(long)bhc * 64 + d] = cum;
  __syncthreads();
  {  // role switch: thread = time index
    int t = d;
    float ssq = 0.f;
    #pragma unroll
    for (int dd = 0; dd < 64; ++dd) { float kv = kL[t * 65 + dd]; ssq += kv * kv; }
    rn[t] = 1.f / fmaxf(sqrtf(ssq), 1e-12f);
  }
  __syncthreads();
  const float lend = cum;
  const long obase = (long)bhc * 4096;
  for (int tg = 0; tg < 8; ++tg) {
    unsigned short kh8[8], vt8[8];
    #pragma unroll
    for (int j = 0; j < 8; ++j) {
      int t = tg * 8 + j;
      long g = rowbase + (long)t * 2048;
      float lam = lamL[t * 64 + d];
      float kn = kL[t * 65 + d] * rn[t];
      float qv = bf2f(Cb[g + off]);
      float vv = bf2f(Cb[g + 1024 + off]);
      qt[obase + t * 64 + d] = f2bf(qv * lam);
      kt[obase + t * 64 + d] = f2bf(kn / lam);
      kh8[j] = f2bf(kn * (lend / lam));
      vt8[j] = f2bf(vv);
    }
    uint4 pk, pv;
    pk.x = (unsigned)kh8[0] | ((unsigned)kh8[1] << 16); pk.y = (unsigned)kh8[2] | ((unsigned)kh8[3] << 16);
    pk.z = (unsigned)kh8[4] | ((unsigned)kh8[5] << 16); pk.w = (unsigned)kh8[6] | ((unsigned)kh8[7] << 16);
    pv.x = (unsigned)vt8[0] | ((unsigned)vt8[1] << 16); pv.y = (unsigned)vt8[2] | ((unsigned)vt8[3] << 16);
    pv.z = (unsigned)vt8[4] | ((unsigned)vt8[5] << 16); pv.w = (unsigned)vt8[6] | ((unsigned)vt8[7] << 16);
    *(uint4*)(khat + obase + d * 64 + tg * 8) = pk;
    *(uint4*)(vtb  + obase + d * 64 + tg * 8) = pv;
  }
}

// ---------------- K4: intra-chunk attention + chunk transition ---------------
__global__ __launch_bounds__(256) void intra_kernel(const unsigned short* __restrict__ qt,
                                                    const unsigned short* __restrict__ kt,
                                                    const unsigned short* __restrict__ vtb,
                                                    const unsigned short* __restrict__ khat,
                                                    float* __restrict__ Ointra,
                                                    unsigned short* __restrict__ Tt) {
  const int bhc = blockIdx.x;
  const long base = (long)bhc * 4096;
  __shared__ __align__(16) unsigned short Qs[4096], Ks[4096], Vs[4096], Hs[4096], Ps[4096];
  const int tid = threadIdx.x;
  {
    const uint4* gq = (const uint4*)(qt + base);   uint4* lq = (uint4*)Qs;
    const uint4* gk = (const uint4*)(kt + base);   uint4* lk = (uint4*)Ks;
    const uint4* gv = (const uint4*)(vtb + base);  uint4* lv = (uint4*)Vs;
    const uint4* gh = (const uint4*)(khat + base); uint4* lh = (uint4*)Hs;
    lq[tid] = gq[tid]; lq[tid + 256] = gq[tid + 256];
    lk[tid] = gk[tid]; lk[tid + 256] = gk[tid + 256];
    lv[tid] = gv[tid]; lv[tid + 256] = gv[tid + 256];
    lh[tid] = gh[tid]; lh[tid + 256] = gh[tid + 256];
  }
  __syncthreads();
  const int wave = tid >> 6, lane = tid & 63, quad = lane >> 4, l16 = lane & 15;
  const int mrow = wave * 16 + l16;
  // P = q~ k~^T, causal mask, -> LDS bf16 (each wave writes+reads only its own 16 rows)
  {
    short8 a0 = *(const short8*)&Qs[mrow * 64 + quad * 8];
    short8 a1 = *(const short8*)&Qs[mrow * 64 + 32 + quad * 8];
    #pragma unroll
    for (int nt = 0; nt < 4; ++nt) {
      short8 b0 = *(const short8*)&Ks[(nt * 16 + l16) * 64 + quad * 8];
      short8 b1 = *(const short8*)&Ks[(nt * 16 + l16) * 64 + 32 + quad * 8];
      f32x4 acc = (f32x4){0.f, 0.f, 0.f, 0.f};
      acc = __builtin_amdgcn_mfma_f32_16x16x32_bf16(a0, b0, acc, 0, 0, 0);
      acc = __builtin_amdgcn_mfma_f32_16x16x32_bf16(a1, b1, acc, 0, 0, 0);
      #pragma unroll
      for (int r = 0; r < 4; ++r) {
        int t = wave * 16 + quad * 4 + r, u = nt * 16 + l16;
        Ps[t * 64 + u] = (u <= t) ? f2bf(acc[r]) : (unsigned short)0;
      }
    }
  }
  // O_intra = P V   (same-wave LDS RAW; lgkmcnt handles it)
  {
    short8 a0 = *(const short8*)&Ps[mrow * 64 + quad * 8];
    short8 a1 = *(const short8*)&Ps[mrow * 64 + 32 + quad * 8];
    #pragma unroll
    for (int nt = 0; nt < 4; ++nt) {
      short8 b0 = *(const short8*)&Vs[(nt * 16 + l16) * 64 + quad * 8];
      short8 b1 = *(const short8*)&Vs[(nt * 16 + l16) * 64 + 32 + quad * 8];
      f32x4 acc = (f32x4){0.f, 0.f, 0.f, 0.f};
      acc = __builtin_amdgcn_mfma_f32_16x16x32_bf16(a0, b0, acc, 0, 0, 0);
      acc = __builtin_amdgcn_mfma_f32_16x16x32_bf16(a1, b1, acc, 0, 0, 0);
      #pragma unroll
      for (int r = 0; r < 4; ++r) {
        int t = wave * 16 + quad * 4 + r, i = nt * 16 + l16;
        Ointra[base + t * 64 + i] = acc[r];
      }
    }
  }
  // Tt = V^T Khat : Tt[i][j] = sum_u Vs[i][u] * Hs[j][u]  (bf16 store)
  {
    short8 a0 = *(const short8*)&Vs[mrow * 64 + quad * 8];
    short8 a1 = *(const short8*)&Vs[mrow * 64 + 32 + quad * 8];
    #pragma unroll
    for (int nt = 0; nt < 4; ++nt) {
      short8 b0 = *(const short8*)&Hs[(nt * 16 + l16) * 64 + quad * 8];
      short8 b1 = *(const short8*)&Hs[(nt * 16 + l16) * 64 + 32 + quad * 8];
      f32x4 acc = (f32x4){0.f, 0.f, 0.f, 0.f};
      acc = __builtin_amdgcn_mfma_f32_16x16x32_bf16(a0, b0, acc, 0, 0, 0);
      acc = __builtin_amdgcn_mfma_f32_16x16x32_bf16(a1, b1, acc, 0, 0, 0);
      #pragma unroll
      for (int r = 0; r < 4; ++r) {
        int i = wave * 16 + quad * 4 + r, j = nt * 16 + l16;
        Tt[base + i * 64 + j] = f2bf(acc[r]);
      }
    }
  }
}

// ---------------- K5: chunk-state scan (S^T per (b,h); 64 sequential chunks) -
__global__ __launch_bounds__(256) void scan_kernel(const unsigned short* __restrict__ Tt,
                                                   const float* __restrict__ Dvec,
                                                   unsigned short* __restrict__ Sst) {
  const int bh = blockIdx.x, tid = threadIdx.x;
  const int j = tid & 63;  // e = r*256 + tid -> e & 63 == tid & 63
  float S[16];
  #pragma unroll
  for (int r = 0; r < 16; ++r) S[r] = 0.f;
  for (int c = 0; c < 64; ++c) {
    const long base = ((long)bh * 64 + c) * 4096;
    const float dj = Dvec[((long)bh * 64 + c) * 64 + j];
    #pragma unroll
    for (int r = 0; r < 16; ++r) {
      int e = r * 256 + tid;
      Sst[base + e] = f2bf(S[r]);           // state BEFORE chunk c
      S[r] = dj * S[r] + bf2f(Tt[base + e]);
    }
  }
}

// ---------------- K6: O = O_intra + q~ @ S_prev, pack to [tok][h*64+i] bf16 --
__global__ __launch_bounds__(256) void combine_kernel(const unsigned short* __restrict__ qt,
                                                      const unsigned short* __restrict__ Sst,
                                                      const float* __restrict__ Ointra,
                                                      unsigned short* __restrict__ O) {
  const int bhc = blockIdx.x;
  const int c = bhc & 63, bh = bhc >> 6;
  const int h = bh & 7, b = bh >> 3;
  const long base = (long)bhc * 4096;
  __shared__ __align__(16) unsigned short Qs[4096], Sb[4096];
  const int tid = threadIdx.x;
  {
    const uint4* gq = (const uint4*)(qt + base);  uint4* lq = (uint4*)Qs;
    const uint4* gs = (const uint4*)(Sst + base); uint4* ls = (uint4*)Sb;
    lq[tid] = gq[tid]; lq[tid + 256] = gq[tid + 256];
    ls[tid] = gs[tid]; ls[tid + 256] = gs[tid + 256];
  }
  __syncthreads();
  const int wave = tid >> 6, lane = tid & 63, quad = lane >> 4, l16 = lane & 15;
  const int mrow = wave * 16 + l16;
  short8 a0 = *(const short8*)&Qs[mrow * 64 + quad * 8];
  short8 a1 = *(const short8*)&Qs[mrow * 64 + 32 + quad * 8];
  #pragma unroll
  for (int nt = 0; nt < 4; ++nt) {
    f32x4 acc;
    #pragma unroll
    for (int r = 0; r < 4; ++r) {
      int t = wave * 16 + quad * 4 + r, i = nt * 16 + l16;
      acc[r] = Ointra[base + t * 64 + i];
    }
    short8 b0 = *(const short8*)&Sb[(nt * 16 + l16) * 64 + quad * 8];
    short8 b1 = *(const short8*)&Sb[(nt * 16 + l16) * 64 + 32 + quad * 8];
    acc = __builtin_amdgcn_mfma_f32_16x16x32_bf16(a0, b0, acc, 0, 0, 0);
    acc = __builtin_amdgcn_mfma_f32_16x16x32_bf16(a1, b1, acc, 0, 0, 0);
    #pragma unroll
    for (int r = 0; r < 4; ++r) {
      int t = wave * 16 + quad * 4 + r, i = nt * 16 + l16;
      O[((long)(b * 4096 + c * 64 + t)) * 512 + h * 64 + i] = f2bf(acc[r]);
    }
  }
}

// ---------------- host ----------------
// Workspace layout (KB offsets), total 153088 KB ~= 149.5 MB, with lifetime aliasing:
//   0       Wt    4096 KB   (weights, whole call)
//   4096    Wot   1024 KB
//   5120    Dvec  512 KB
//   5632    qt    16384 KB  (prep -> intra,combine)
//   22016   kt    16384 KB  (prep -> intra)
//   38400   vtb   16384 KB  (prep -> intra)
//   54784   xn    32768 KB  (ln -> gemm1); reused after gemm1:
//             khat @54784 (16384, prep -> intra), Ob @71168 (16384, combine -> gemm2)
//   87552   Cb    65536 KB  (gemm1 -> prep); reused after prep:
//             Ointra @87552 (32768 fp32), Ttb @120320 (16384 bf16), Sst @136704 (16384 bf16)
extern "C" void kernel_launch(void* const* d_in, const int* in_sizes, int n_in,
                              void* d_out, int out_size, void* d_ws, size_t ws_size,
                              hipStream_t stream) {
  const float* x     = (const float*)d_in[0];
  const float* Wq    = (const float*)d_in[1];
  const float* Wk    = (const float*)d_in[2];
  const float* Wv    = (const float*)d_in[3];
  const float* Wa    = (const float*)d_in[4];
  const float* ba    = (const float*)d_in[5];
  const float* Wo    = (const float*)d_in[6];
  const float* gamma = (const float*)d_in[7];
  const float* beta  = (const float*)d_in[8];
  float* out = (float*)d_out;

  char* ws = (char*)d_ws;
  const size_t KB = 1024;
  unsigned short* Wt     = (unsigned short*)(ws + 0 * KB);
  unsigned short* Wot    = (unsigned short*)(ws + 4096 * KB);
  float*          Dvec   = (float*)         (ws + 5120 * KB);
  unsigned short* qt     = (unsigned short*)(ws + 5632 * KB);
  unsigned short* ktb    = (unsigned short*)(ws + 22016 * KB);
  unsigned short* vtb    = (unsigned short*)(ws + 38400 * KB);
  unsigned short* xn     = (unsigned short*)(ws + 54784 * KB);
  unsigned short* khat   = (unsigned short*)(ws + 54784 * KB);  // aliases xn (dead)
  unsigned short* Ob     = (unsigned short*)(ws + 71168 * KB);  // aliases xn tail (dead)
  unsigned short* Cb     = (unsigned short*)(ws + 87552 * KB);
  float*          Ointra = (float*)         (ws + 87552 * KB);  // aliases Cb (dead)
  unsigned short* Ttb    = (unsigned short*)(ws + 120320 * KB); // aliases Cb (dead)
  unsigned short* Sst    = (unsigned short*)(ws + 136704 * KB); // aliases Cb (dead)

  transpose_bf16<<<dim3(16, 32), 256, 0, stream>>>(Wq, Wt + (size_t)0 * 512 * 1024, 1024, 512);
  transpose_bf16<<<dim3(16, 32), 256, 0, stream>>>(Wk, Wt + (size_t)1 * 512 * 1024, 1024, 512);
  transpose_bf16<<<dim3(16, 32), 256, 0, stream>>>(Wv, Wt + (size_t)2 * 512 * 1024, 1024, 512);
  transpose_bf16<<<dim3(16, 32), 256, 0, stream>>>(Wa, Wt + (size_t)3 * 512 * 1024, 1024, 512);
  transpose_bf16<<<dim3(32, 16), 256, 0, stream>>>(Wo, Wot, 512, 1024);
  ln_kernel<<<NTOK, 256, 0, stream>>>(x, gamma, beta, xn);
  gemm_bt<0><<<dim3(NTOK / 128, 2048 / 128), 256, 0, stream>>>(xn, Wt, Cb, nullptr, nullptr, NTOK, 2048, 1024);
  prep_kernel<<<NBHC, 64, 0, stream>>>(Cb, ba, qt, ktb, khat, vtb, Dvec);
  intra_kernel<<<NBHC, 256, 0, stream>>>(qt, ktb, vtb, khat, Ointra, Ttb);
  scan_kernel<<<32, 256, 0, stream>>>(Ttb, Dvec, Sst);
  combine_kernel<<<NBHC, 256, 0, stream>>>(qt, Sst, Ointra, Ob);
  gemm_bt<1><<<dim3(NTOK / 128, 1024 / 128), 256, 0, stream>>>(Ob, Wot, nullptr, out, x, NTOK, 1024, 512);
}

// Round 4
// 346.110 us; speedup vs baseline: 1.1417x; 1.1417x over previous
//
#include <hip/hip_runtime.h>
#include <stdint.h>

#define NTOK   16384      // B*T = 4*4096
#define DM     1024
#define DI     512
#define NH     8
#define DH     64
#define CHUNK  64
#define NCH    64         // T / CHUNK
#define NBHC   2048       // B*H*NCH

using short8 = __attribute__((ext_vector_type(8))) short;
using f32x4  = __attribute__((ext_vector_type(4))) float;

__device__ __forceinline__ unsigned short f2bf(float f) {
  union { float f; unsigned int u; } x; x.f = f;
  unsigned int u = x.u;
  return (unsigned short)((u + 0x7fffu + ((u >> 16) & 1u)) >> 16);
}
__device__ __forceinline__ float bf2f(unsigned short h) {
  union { unsigned int u; float f; } x; x.u = ((unsigned int)h) << 16; return x.f;
}

typedef const __attribute__((address_space(1))) void* gp1_t;
typedef __attribute__((address_space(3))) void* lp3_t;
__device__ __forceinline__ void gload_lds16(const void* g, void* l) {
  __builtin_amdgcn_global_load_lds((gp1_t)g, (lp3_t)l, 16, 0, 0);
}

// ---------------- K0: fp32 -> bf16 transpose (out[n][k] = in[k][n]) ----------
__global__ __launch_bounds__(256) void transpose_bf16(const float* __restrict__ in,
                                                      unsigned short* __restrict__ out,
                                                      int R, int C) {
  __shared__ float tile[32][33];
  int bx = blockIdx.x * 32;           // col base (output row base)
  int by = blockIdx.y * 32;           // row base
  int tx = threadIdx.x & 31, ty = threadIdx.x >> 5;
  #pragma unroll
  for (int r = ty; r < 32; r += 8) tile[r][tx] = in[(long)(by + r) * C + bx + tx];
  __syncthreads();
  #pragma unroll
  for (int r = ty; r < 32; r += 8) out[(long)(bx + r) * R + by + tx] = f2bf(tile[tx][r]);
}

// ---------------- K1: LayerNorm -> bf16 --------------------------------------
__global__ __launch_bounds__(256) void ln_kernel(const float* __restrict__ x,
                                                 const float* __restrict__ gamma,
                                                 const float* __restrict__ beta,
                                                 unsigned short* __restrict__ xn) {
  const int row = blockIdx.x, tid = threadIdx.x;
  float4 v = ((const float4*)(x + (long)row * DM))[tid];
  float s  = v.x + v.y + v.z + v.w;
  float ss = v.x * v.x + v.y * v.y + v.z * v.z + v.w * v.w;
  #pragma unroll
  for (int off = 32; off > 0; off >>= 1) { s += __shfl_down(s, off); ss += __shfl_down(ss, off); }
  __shared__ float rs_[4], rss_[4];
  int wave = tid >> 6, lane = tid & 63;
  if (lane == 0) { rs_[wave] = s; rss_[wave] = ss; }
  __syncthreads();
  s  = rs_[0] + rs_[1] + rs_[2] + rs_[3];
  ss = rss_[0] + rss_[1] + rss_[2] + rss_[3];
  float mu   = s * (1.f / DM);
  float var  = ss * (1.f / DM) - mu * mu;
  float rstd = rsqrtf(var + 1e-5f);
  int idx = tid * 4;
  float xv[4] = {v.x, v.y, v.z, v.w};
  unsigned short o[4];
  #pragma unroll
  for (int j = 0; j < 4; ++j) o[j] = f2bf((xv[j] - mu) * rstd * gamma[idx + j] + beta[idx + j]);
  uint2 pk; pk.x = (unsigned)o[0] | ((unsigned)o[1] << 16); pk.y = (unsigned)o[2] | ((unsigned)o[3] << 16);
  *(uint2*)(xn + (long)row * DM + idx) = pk;
}

// ---------------- GEMM: C[M][N] = A(bf16 MxK) * Bt(bf16 NxK)^T ---------------
// MODE 0: store bf16 to Cb.  MODE 1: store fp32 + residual to Cf.
template <int MODE>
__global__ __launch_bounds__(256) void gemm_bt(const unsigned short* __restrict__ A,
                                               const unsigned short* __restrict__ Bt,
                                               unsigned short* __restrict__ Cb,
                                               float* __restrict__ Cf,
                                               const float* __restrict__ resid,
                                               int M, int N, int K) {
  __shared__ __align__(16) unsigned short As[128 * 32];
  __shared__ __align__(16) unsigned short Bs[128 * 32];
  const int tid = threadIdx.x;
  const int wave = tid >> 6, lane = tid & 63;
  const int quad = lane >> 4, l16 = lane & 15;
  const int m0 = blockIdx.x * 128, n0 = blockIdx.y * 128;
  const int wm = (wave & 1) * 64, wn = (wave >> 1) * 64;

  const int c0 = tid, c1 = tid + 256;
  const unsigned short* Ag0 = A + (long)(m0 + (c0 >> 2)) * K + (c0 & 3) * 8;
  const unsigned short* Ag1 = A + (long)(m0 + (c1 >> 2)) * K + (c1 & 3) * 8;
  const unsigned short* Bg0 = Bt + (long)(n0 + (c0 >> 2)) * K + (c0 & 3) * 8;
  const unsigned short* Bg1 = Bt + (long)(n0 + (c1 >> 2)) * K + (c1 & 3) * 8;

  f32x4 acc[4][4];
  #pragma unroll
  for (int i = 0; i < 4; ++i)
    #pragma unroll
    for (int j = 0; j < 4; ++j) acc[i][j] = (f32x4){0.f, 0.f, 0.f, 0.f};

  for (int k0 = 0; k0 < K; k0 += 32) {
    __syncthreads();
    gload_lds16(Ag0 + k0, &As[c0 * 8]);
    gload_lds16(Ag1 + k0, &As[c1 * 8]);
    gload_lds16(Bg0 + k0, &Bs[c0 * 8]);
    gload_lds16(Bg1 + k0, &Bs[c1 * 8]);
    __syncthreads();
    short8 a[4], b[4];
    #pragma unroll
    for (int mt = 0; mt < 4; ++mt) a[mt] = *(const short8*)&As[(wm + mt * 16 + l16) * 32 + quad * 8];
    #pragma unroll
    for (int nt = 0; nt < 4; ++nt) b[nt] = *(const short8*)&Bs[(wn + nt * 16 + l16) * 32 + quad * 8];
    #pragma unroll
    for (int mt = 0; mt < 4; ++mt)
      #pragma unroll
      for (int nt = 0; nt < 4; ++nt)
        acc[mt][nt] = __builtin_amdgcn_mfma_f32_16x16x32_bf16(a[mt], b[nt], acc[mt][nt], 0, 0, 0);
  }
  #pragma unroll
  for (int mt = 0; mt < 4; ++mt)
    #pragma unroll
    for (int nt = 0; nt < 4; ++nt)
      #pragma unroll
      for (int r = 0; r < 4; ++r) {
        int row = m0 + wm + mt * 16 + quad * 4 + r;
        int col = n0 + wn + nt * 16 + l16;
        float v = acc[mt][nt][r];
        if (MODE == 0) {
          Cb[(long)row * N + col] = f2bf(v);
        } else {
          Cf[(long)row * N + col] = v + resid[(long)row * N + col];
        }
      }
}

// ---------------- K3: fused per-chunk prep + intra-chunk attention -----------
// Cb row layout (bf16): [q 0..511 | k 512..1023 | v 1024..1535 | alog 1536..2047]
// LDS: Qb,Kb row-major [t][d] (for P = q~ k~^T, contraction over d);
//      Vt,Ht TRANSPOSED [d][t] stride 72 (for PV and V^T K^, contraction over t).
#define TS 72   // transposed-tile row stride (shorts); 144 B rows -> 16B-aligned b128 reads
__global__ __launch_bounds__(256) void prep_intra_kernel(const unsigned short* __restrict__ Cb,
                                                         const float* __restrict__ ba,
                                                         unsigned short* __restrict__ qt,
                                                         float* __restrict__ Dvec,
                                                         unsigned short* __restrict__ Ointra,
                                                         unsigned short* __restrict__ Tt) {
  const int bhc = blockIdx.x;
  const int c = bhc & 63, bh = bhc >> 6;
  const int h = bh & 7, b = bh >> 3;
  const int tid = threadIdx.x;
  __shared__ __align__(16) unsigned short Qb[4096], Kb[4096], Ab[4096];
  __shared__ __align__(16) unsigned short Vt[64 * TS], Ht[64 * TS];
  __shared__ float lamF[4096];
  __shared__ float rnF[64];
  const long rowbase = ((long)(b * 4096 + c * 64)) * 2048;
  const int hoff = h * 64;

  if (tid < 64) rnF[tid] = 0.f;
  __syncthreads();

  // cooperative tile load (row t = u>>3, 16B part p = u&7); k ssq accumulated in flight;
  // V written TRANSPOSED into Vt[d][t]
  #pragma unroll
  for (int chunk = 0; chunk < 2; ++chunk) {
    int u = chunk * 256 + tid;
    int t = u >> 3, p = u & 7;
    long g = rowbase + (long)t * 2048 + hoff + p * 8;
    uint4 q4 = *(const uint4*)(Cb + g);
    uint4 k4 = *(const uint4*)(Cb + g + 512);
    uint4 v4 = *(const uint4*)(Cb + g + 1024);
    uint4 a4 = *(const uint4*)(Cb + g + 1536);
    *(uint4*)&Qb[u * 8] = q4;
    *(uint4*)&Kb[u * 8] = k4;
    *(uint4*)&Ab[u * 8] = a4;
    const unsigned short* vs = (const unsigned short*)&v4;
    #pragma unroll
    for (int j = 0; j < 8; ++j) Vt[(p * 8 + j) * TS + t] = vs[j];
    const unsigned short* ks = (const unsigned short*)&k4;
    float ssq = 0.f;
    #pragma unroll
    for (int j = 0; j < 8; ++j) { float kv = bf2f(ks[j]); ssq += kv * kv; }
    atomicAdd(&rnF[t], ssq);
  }
  __syncthreads();

  // sigmoid (all 256 threads); e = j*256+tid -> column d = tid&63 fixed
  {
    const float bav = ba[hoff + (tid & 63)];
    #pragma unroll
    for (int j = 0; j < 16; ++j) {
      int e = j * 256 + tid;
      float z = bf2f(Ab[e]) + bav;
      lamF[e] = 1.f / (1.f + __expf(-z));
    }
  }
  __syncthreads();

  // wave0: cumprod per channel d (in-place) + Dvec; wave1: finalize rn
  if (tid < 64) {
    int d = tid; float cum = 1.f;
    for (int t = 0; t < 64; ++t) { cum *= lamF[t * 64 + d]; lamF[t * 64 + d] = cum; }
    Dvec[(long)bhc * 64 + d] = cum;
  } else if (tid < 128) {
    int t = tid - 64;
    rnF[t] = 1.f / fmaxf(sqrtf(rnF[t]), 1e-12f);
  }
  __syncthreads();

  // transform in LDS: q~ = q*lam (row-major); k~ = kn/lam (row-major);
  // khat = kn*lend/lam written TRANSPOSED into Ht[d][t]
  {
    const int d = tid & 63;
    const float lend = lamF[63 * 64 + d];
    #pragma unroll
    for (int j = 0; j < 16; ++j) {
      int e = j * 256 + tid;
      int t = e >> 6;                 // wave-uniform
      float lam = lamF[e];
      float rl = 1.f / lam;
      float kn = bf2f(Kb[e]) * rnF[t];
      Qb[e] = f2bf(bf2f(Qb[e]) * lam);
      Kb[e] = f2bf(kn * rl);
      Ht[d * TS + t] = f2bf(kn * lend * rl);
    }
  }
  __syncthreads();

  // write qt (coalesced uint4 from transformed Qb)
  {
    const long obase = (long)bhc * 4096;
    uint4* gq = (uint4*)(qt + obase);
    const uint4* lq = (const uint4*)Qb;
    gq[tid] = lq[tid]; gq[tid + 256] = lq[tid + 256];
  }

  const long base = (long)bhc * 4096;
  const int wave = tid >> 6, lane = tid & 63, quad = lane >> 4, l16 = lane & 15;
  const int mrow = wave * 16 + l16;
  unsigned short* Ps = Ab;   // alog dead -> reuse as P tile

  // P = q~ k~^T (contraction over d), causal mask -> LDS bf16
  // (each wave writes+reads only its own 16 rows of Ps)
  {
    short8 a0 = *(const short8*)&Qb[mrow * 64 + quad * 8];
    short8 a1 = *(const short8*)&Qb[mrow * 64 + 32 + quad * 8];
    #pragma unroll
    for (int nt = 0; nt < 4; ++nt) {
      short8 b0 = *(const short8*)&Kb[(nt * 16 + l16) * 64 + quad * 8];
      short8 b1 = *(const short8*)&Kb[(nt * 16 + l16) * 64 + 32 + quad * 8];
      f32x4 acc = (f32x4){0.f, 0.f, 0.f, 0.f};
      acc = __builtin_amdgcn_mfma_f32_16x16x32_bf16(a0, b0, acc, 0, 0, 0);
      acc = __builtin_amdgcn_mfma_f32_16x16x32_bf16(a1, b1, acc, 0, 0, 0);
      #pragma unroll
      for (int r = 0; r < 4; ++r) {
        int t = wave * 16 + quad * 4 + r, u = nt * 16 + l16;
        Ps[t * 64 + u] = (u <= t) ? f2bf(acc[r]) : (unsigned short)0;
      }
    }
  }
  // O_intra[t][i] = sum_u P[t][u] * V[u][i]: A = P rows t (k=u), B = Vt rows i (k=u)
  {
    short8 a0 = *(const short8*)&Ps[mrow * 64 + quad * 8];
    short8 a1 = *(const short8*)&Ps[mrow * 64 + 32 + quad * 8];
    #pragma unroll
    for (int nt = 0; nt < 4; ++nt) {
      short8 b0 = *(const short8*)&Vt[(nt * 16 + l16) * TS + quad * 8];
      short8 b1 = *(const short8*)&Vt[(nt * 16 + l16) * TS + 32 + quad * 8];
      f32x4 acc = (f32x4){0.f, 0.f, 0.f, 0.f};
      acc = __builtin_amdgcn_mfma_f32_16x16x32_bf16(a0, b0, acc, 0, 0, 0);
      acc = __builtin_amdgcn_mfma_f32_16x16x32_bf16(a1, b1, acc, 0, 0, 0);
      #pragma unroll
      for (int r = 0; r < 4; ++r) {
        int t = wave * 16 + quad * 4 + r, i = nt * 16 + l16;
        Ointra[base + t * 64 + i] = f2bf(acc[r]);
      }
    }
  }
  // Tt[i][j] = sum_t V^T[i][t] * Khat^T[j][t]: A = Vt rows i, B = Ht rows j
  {
    short8 a0 = *(const short8*)&Vt[mrow * TS + quad * 8];
    short8 a1 = *(const short8*)&Vt[mrow * TS + 32 + quad * 8];
    #pragma unroll
    for (int nt = 0; nt < 4; ++nt) {
      short8 b0 = *(const short8*)&Ht[(nt * 16 + l16) * TS + quad * 8];
      short8 b1 = *(const short8*)&Ht[(nt * 16 + l16) * TS + 32 + quad * 8];
      f32x4 acc = (f32x4){0.f, 0.f, 0.f, 0.f};
      acc = __builtin_amdgcn_mfma_f32_16x16x32_bf16(a0, b0, acc, 0, 0, 0);
      acc = __builtin_amdgcn_mfma_f32_16x16x32_bf16(a1, b1, acc, 0, 0, 0);
      #pragma unroll
      for (int r = 0; r < 4; ++r) {
        int i = wave * 16 + quad * 4 + r, j = nt * 16 + l16;
        Tt[base + i * 64 + j] = f2bf(acc[r]);
      }
    }
  }
}

// ---------------- K5: chunk-state scan, element-parallel ---------------------
// S_c[i][j] = d_j * S_{c-1}[i][j] + T_c[i][j]; independent per element.
__global__ __launch_bounds__(256) void scan_kernel(const unsigned short* __restrict__ Tt,
                                                   const float* __restrict__ Dvec,
                                                   unsigned short* __restrict__ Sst) {
  const int bh = blockIdx.x;
  const int e = blockIdx.y * 256 + threadIdx.x;
  const int j = e & 63;
  float S = 0.f;
  for (int c = 0; c < 64; ++c) {
    const long idx = ((long)(bh * 64 + c)) * 4096 + e;
    const float dj = Dvec[((long)(bh * 64 + c)) * 64 + j];
    Sst[idx] = f2bf(S);                 // state BEFORE chunk c
    S = dj * S + bf2f(Tt[idx]);
  }
}

// ---------------- K6: O = O_intra + q~ @ S_prev, pack to [tok][h*64+i] bf16 --
__global__ __launch_bounds__(256) void combine_kernel(const unsigned short* __restrict__ qt,
                                                      const unsigned short* __restrict__ Sst,
                                                      const unsigned short* __restrict__ Ointra,
                                                      unsigned short* __restrict__ O) {
  const int bhc = blockIdx.x;
  const int c = bhc & 63, bh = bhc >> 6;
  const int h = bh & 7, b = bh >> 3;
  const long base = (long)bhc * 4096;
  __shared__ __align__(16) unsigned short Qs[4096], Sb[4096];
  const int tid = threadIdx.x;
  {
    const uint4* gq = (const uint4*)(qt + base);  uint4* lq = (uint4*)Qs;
    const uint4* gs = (const uint4*)(Sst + base); uint4* ls = (uint4*)Sb;
    lq[tid] = gq[tid]; lq[tid + 256] = gq[tid + 256];
    ls[tid] = gs[tid]; ls[tid + 256] = gs[tid + 256];
  }
  __syncthreads();
  const int wave = tid >> 6, lane = tid & 63, quad = lane >> 4, l16 = lane & 15;
  const int mrow = wave * 16 + l16;
  short8 a0 = *(const short8*)&Qs[mrow * 64 + quad * 8];
  short8 a1 = *(const short8*)&Qs[mrow * 64 + 32 + quad * 8];
  #pragma unroll
  for (int nt = 0; nt < 4; ++nt) {
    f32x4 acc;
    #pragma unroll
    for (int r = 0; r < 4; ++r) {
      int t = wave * 16 + quad * 4 + r, i = nt * 16 + l16;
      acc[r] = bf2f(Ointra[base + t * 64 + i]);
    }
    short8 b0 = *(const short8*)&Sb[(nt * 16 + l16) * 64 + quad * 8];
    short8 b1 = *(const short8*)&Sb[(nt * 16 + l16) * 64 + 32 + quad * 8];
    acc = __builtin_amdgcn_mfma_f32_16x16x32_bf16(a0, b0, acc, 0, 0, 0);
    acc = __builtin_amdgcn_mfma_f32_16x16x32_bf16(a1, b1, acc, 0, 0, 0);
    #pragma unroll
    for (int r = 0; r < 4; ++r) {
      int t = wave * 16 + quad * 4 + r, i = nt * 16 + l16;
      O[((long)(b * 4096 + c * 64 + t)) * 512 + h * 64 + i] = f2bf(acc[r]);
    }
  }
}

// ---------------- host ----------------
// Workspace layout (KB offsets), total 153088 KB, lifetime-aliased:
//   0       Wt     4096 KB   (whole call)
//   4096    Wot    1024 KB
//   5120    Dvec   512 KB
//   5632    qt     16384 KB  (prep_intra -> combine)
//   22016   Ttb    16384 KB  (prep_intra -> scan)
//   38400   Sst    16384 KB  (scan -> combine)
//   54784   xn     32768 KB  (ln -> gemm1); reused after gemm1:
//             Ointra @54784 (16384 KB, prep_intra -> combine)
//             Ob     @71168 (16384 KB, combine -> gemm2)
//   87552   Cb     65536 KB  (gemm1 -> prep_intra)
extern "C" void kernel_launch(void* const* d_in, const int* in_sizes, int n_in,
                              void* d_out, int out_size, void* d_ws, size_t ws_size,
                              hipStream_t stream) {
  const float* x     = (const float*)d_in[0];
  const float* Wq    = (const float*)d_in[1];
  const float* Wk    = (const float*)d_in[2];
  const float* Wv    = (const float*)d_in[3];
  const float* Wa    = (const float*)d_in[4];
  const float* ba    = (const float*)d_in[5];
  const float* Wo    = (const float*)d_in[6];
  const float* gamma = (const float*)d_in[7];
  const float* beta  = (const float*)d_in[8];
  float* out = (float*)d_out;

  char* ws = (char*)d_ws;
  const size_t KB = 1024;
  unsigned short* Wt     = (unsigned short*)(ws + 0 * KB);
  unsigned short* Wot    = (unsigned short*)(ws + 4096 * KB);
  float*          Dvec   = (float*)         (ws + 5120 * KB);
  unsigned short* qt     = (unsigned short*)(ws + 5632 * KB);
  unsigned short* Ttb    = (unsigned short*)(ws + 22016 * KB);
  unsigned short* Sst    = (unsigned short*)(ws + 38400 * KB);
  unsigned short* xn     = (unsigned short*)(ws + 54784 * KB);
  unsigned short* Ointra = (unsigned short*)(ws + 54784 * KB);  // aliases xn (dead after gemm1)
  unsigned short* Ob     = (unsigned short*)(ws + 71168 * KB);  // aliases xn tail (dead)
  unsigned short* Cb     = (unsigned short*)(ws + 87552 * KB);

  transpose_bf16<<<dim3(16, 32), 256, 0, stream>>>(Wq, Wt + (size_t)0 * 512 * 1024, 1024, 512);
  transpose_bf16<<<dim3(16, 32), 256, 0, stream>>>(Wk, Wt + (size_t)1 * 512 * 1024, 1024, 512);
  transpose_bf16<<<dim3(16, 32), 256, 0, stream>>>(Wv, Wt + (size_t)2 * 512 * 1024, 1024, 512);
  transpose_bf16<<<dim3(16, 32), 256, 0, stream>>>(Wa, Wt + (size_t)3 * 512 * 1024, 1024, 512);
  transpose_bf16<<<dim3(32, 16), 256, 0, stream>>>(Wo, Wot, 512, 1024);
  ln_kernel<<<NTOK, 256, 0, stream>>>(x, gamma, beta, xn);
  gemm_bt<0><<<dim3(NTOK / 128, 2048 / 128), 256, 0, stream>>>(xn, Wt, Cb, nullptr, nullptr, NTOK, 2048, 1024);
  prep_intra_kernel<<<NBHC, 256, 0, stream>>>(Cb, ba, qt, Dvec, Ointra, Ttb);
  scan_kernel<<<dim3(32, 16), 256, 0, stream>>>(Ttb, Dvec, Sst);
  combine_kernel<<<NBHC, 256, 0, stream>>>(qt, Sst, Ointra, Ob);
  gemm_bt<1><<<dim3(NTOK / 128, 1024 / 128), 256, 0, stream>>>(Ob, Wot, nullptr, out, x, NTOK, 1024, 512);
}

// Round 5
// 334.340 us; speedup vs baseline: 1.1819x; 1.0352x over previous
//
#include <hip/hip_runtime.h>
#include <stdint.h>

#define NTOK   16384      // B*T = 4*4096
#define DM     1024
#define DI     512
#define NH     8
#define DH     64
#define CHUNK  64
#define NCH    64         // T / CHUNK
#define NBHC   2048       // B*H*NCH

using short8 = __attribute__((ext_vector_type(8))) short;
using f32x4  = __attribute__((ext_vector_type(4))) float;

__device__ __forceinline__ unsigned short f2bf(float f) {
  union { float f; unsigned int u; } x; x.f = f;
  unsigned int u = x.u;
  return (unsigned short)((u + 0x7fffu + ((u >> 16) & 1u)) >> 16);
}
__device__ __forceinline__ float bf2f(unsigned short h) {
  union { unsigned int u; float f; } x; x.u = ((unsigned int)h) << 16; return x.f;
}

typedef const __attribute__((address_space(1))) void* gp1_t;
typedef __attribute__((address_space(3))) void* lp3_t;
__device__ __forceinline__ void gload_lds16(const void* g, void* l) {
  __builtin_amdgcn_global_load_lds((gp1_t)g, (lp3_t)l, 16, 0, 0);
}

// ---------------- K0a: 4x fused fp32 -> bf16 transpose (1024x512 each) -------
__global__ __launch_bounds__(256) void transpose4_bf16(const float* __restrict__ Wq,
                                                       const float* __restrict__ Wk,
                                                       const float* __restrict__ Wv,
                                                       const float* __restrict__ Wa,
                                                       unsigned short* __restrict__ out) {
  const int z = blockIdx.z;
  const float* in = (z == 0) ? Wq : (z == 1) ? Wk : (z == 2) ? Wv : Wa;
  unsigned short* o = out + (size_t)z * 512 * 1024;
  __shared__ float tile[32][33];
  int bx = blockIdx.x * 32;           // col base (output row base), C=512
  int by = blockIdx.y * 32;           // row base, R=1024
  int tx = threadIdx.x & 31, ty = threadIdx.x >> 5;
  #pragma unroll
  for (int r = ty; r < 32; r += 8) tile[r][tx] = in[(long)(by + r) * 512 + bx + tx];
  __syncthreads();
  #pragma unroll
  for (int r = ty; r < 32; r += 8) o[(long)(bx + r) * 1024 + by + tx] = f2bf(tile[tx][r]);
}

// ---------------- K0b: Wo transpose (512x1024 -> 1024x512) -------------------
__global__ __launch_bounds__(256) void transpose_bf16(const float* __restrict__ in,
                                                      unsigned short* __restrict__ out,
                                                      int R, int C) {
  __shared__ float tile[32][33];
  int bx = blockIdx.x * 32;
  int by = blockIdx.y * 32;
  int tx = threadIdx.x & 31, ty = threadIdx.x >> 5;
  #pragma unroll
  for (int r = ty; r < 32; r += 8) tile[r][tx] = in[(long)(by + r) * C + bx + tx];
  __syncthreads();
  #pragma unroll
  for (int r = ty; r < 32; r += 8) out[(long)(bx + r) * R + by + tx] = f2bf(tile[tx][r]);
}

// ---------------- K1: LayerNorm -> bf16 --------------------------------------
__global__ __launch_bounds__(256) void ln_kernel(const float* __restrict__ x,
                                                 const float* __restrict__ gamma,
                                                 const float* __restrict__ beta,
                                                 unsigned short* __restrict__ xn) {
  const int row = blockIdx.x, tid = threadIdx.x;
  float4 v = ((const float4*)(x + (long)row * DM))[tid];
  float s  = v.x + v.y + v.z + v.w;
  float ss = v.x * v.x + v.y * v.y + v.z * v.z + v.w * v.w;
  #pragma unroll
  for (int off = 32; off > 0; off >>= 1) { s += __shfl_down(s, off); ss += __shfl_down(ss, off); }
  __shared__ float rs_[4], rss_[4];
  int wave = tid >> 6, lane = tid & 63;
  if (lane == 0) { rs_[wave] = s; rss_[wave] = ss; }
  __syncthreads();
  s  = rs_[0] + rs_[1] + rs_[2] + rs_[3];
  ss = rss_[0] + rss_[1] + rss_[2] + rss_[3];
  float mu   = s * (1.f / DM);
  float var  = ss * (1.f / DM) - mu * mu;
  float rstd = rsqrtf(var + 1e-5f);
  int idx = tid * 4;
  float xv[4] = {v.x, v.y, v.z, v.w};
  unsigned short o[4];
  #pragma unroll
  for (int j = 0; j < 4; ++j) o[j] = f2bf((xv[j] - mu) * rstd * gamma[idx + j] + beta[idx + j]);
  uint2 pk; pk.x = (unsigned)o[0] | ((unsigned)o[1] << 16); pk.y = (unsigned)o[2] | ((unsigned)o[3] << 16);
  *(uint2*)(xn + (long)row * DM + idx) = pk;
}

// ---------------- GEMM: C[M][N] = A(bf16 MxK) * Bt(bf16 NxK)^T ---------------
// MODE 0: store bf16 to Cb.  MODE 1: store fp32 + residual to Cf.
// L2 swizzle: groups of 8 M-tiles x all N-tiles. LDS-repacked coalesced epilogue.
#define EPS 136   // epilogue LDS row stride (shorts): 272 B rows -> 16B-aligned b128
template <int MODE>
__global__ __launch_bounds__(256) void gemm_bt(const unsigned short* __restrict__ A,
                                               const unsigned short* __restrict__ Bt,
                                               unsigned short* __restrict__ Cb,
                                               float* __restrict__ Cf,
                                               const float* __restrict__ resid,
                                               int M, int N, int K) {
  __shared__ __align__(16) unsigned short smem[128 * EPS];  // stage (8192) | epi (17408)
  unsigned short* As = smem;          // 128*32
  unsigned short* Bs = smem + 4096;   // 128*32
  const int tid = threadIdx.x;
  const int wave = tid >> 6, lane = tid & 63;
  const int quad = lane >> 4, l16 = lane & 15;

  // block swizzle for L2: consecutive ids cover 8 M-tiles x Nt N-tiles
  const int Nt = gridDim.y;
  int id = blockIdx.x + blockIdx.y * gridDim.x;
  int group = id / (8 * Nt);
  int rem = id - group * (8 * Nt);
  const int m0 = (group * 8 + (rem & 7)) * 128;
  const int n0 = (rem >> 3) * 128;
  const int wm = (wave & 1) * 64, wn = (wave >> 1) * 64;

  const int c0 = tid, c1 = tid + 256;
  const unsigned short* Ag0 = A + (long)(m0 + (c0 >> 2)) * K + (c0 & 3) * 8;
  const unsigned short* Ag1 = A + (long)(m0 + (c1 >> 2)) * K + (c1 & 3) * 8;
  const unsigned short* Bg0 = Bt + (long)(n0 + (c0 >> 2)) * K + (c0 & 3) * 8;
  const unsigned short* Bg1 = Bt + (long)(n0 + (c1 >> 2)) * K + (c1 & 3) * 8;

  f32x4 acc[4][4];
  #pragma unroll
  for (int i = 0; i < 4; ++i)
    #pragma unroll
    for (int j = 0; j < 4; ++j) acc[i][j] = (f32x4){0.f, 0.f, 0.f, 0.f};

  for (int k0 = 0; k0 < K; k0 += 32) {
    __syncthreads();
    gload_lds16(Ag0 + k0, &As[c0 * 8]);
    gload_lds16(Ag1 + k0, &As[c1 * 8]);
    gload_lds16(Bg0 + k0, &Bs[c0 * 8]);
    gload_lds16(Bg1 + k0, &Bs[c1 * 8]);
    __syncthreads();
    short8 a[4], b[4];
    #pragma unroll
    for (int mt = 0; mt < 4; ++mt) a[mt] = *(const short8*)&As[(wm + mt * 16 + l16) * 32 + quad * 8];
    #pragma unroll
    for (int nt = 0; nt < 4; ++nt) b[nt] = *(const short8*)&Bs[(wn + nt * 16 + l16) * 32 + quad * 8];
    #pragma unroll
    for (int mt = 0; mt < 4; ++mt)
      #pragma unroll
      for (int nt = 0; nt < 4; ++nt)
        acc[mt][nt] = __builtin_amdgcn_mfma_f32_16x16x32_bf16(a[mt], b[nt], acc[mt][nt], 0, 0, 0);
  }
  // ---- epilogue: repack through LDS for coalesced global stores ----
  __syncthreads();                       // all waves done reading As/Bs
  unsigned short* epi = smem;
  #pragma unroll
  for (int mt = 0; mt < 4; ++mt)
    #pragma unroll
    for (int nt = 0; nt < 4; ++nt)
      #pragma unroll
      for (int r = 0; r < 4; ++r)
        epi[(wm + mt * 16 + quad * 4 + r) * EPS + wn + nt * 16 + l16] = f2bf(acc[mt][nt][r]);
  __syncthreads();
  if (MODE == 0) {
    #pragma unroll
    for (int i = tid; i < 2048; i += 256) {
      int row = i >> 4, cc = (i & 15) * 8;
      uint4 v = *(const uint4*)&epi[row * EPS + cc];
      *(uint4*)&Cb[(long)(m0 + row) * N + n0 + cc] = v;
    }
  } else {
    #pragma unroll
    for (int i = tid; i < 4096; i += 256) {
      int row = i >> 5, cc = (i & 31) * 4;
      long g = (long)(m0 + row) * N + n0 + cc;
      float4 rv = *(const float4*)&resid[g];
      uint2 pv = *(const uint2*)&epi[row * EPS + cc];
      float4 ov;
      ov.x = bf2f((unsigned short)(pv.x & 0xffffu)) + rv.x;
      ov.y = bf2f((unsigned short)(pv.x >> 16))     + rv.y;
      ov.z = bf2f((unsigned short)(pv.y & 0xffffu)) + rv.z;
      ov.w = bf2f((unsigned short)(pv.y >> 16))     + rv.w;
      *(float4*)&Cf[g] = ov;
    }
  }
}

// ---------------- K3: fused per-chunk prep + intra-chunk attention -----------
// Cb row layout (bf16): [q 0..511 | k 512..1023 | v 1024..1535 | alog 1536..2047]
// LDS: Qb,Kb row-major [t][d]; Vt,Ht transposed [d][t] stride 72;
// lamF fp32 (sigmoid applied at load); Ps overlays lamF after transform.
#define TS 72
__global__ __launch_bounds__(256) void prep_intra_kernel(const unsigned short* __restrict__ Cb,
                                                         const float* __restrict__ ba,
                                                         unsigned short* __restrict__ qt,
                                                         float* __restrict__ Dvec,
                                                         unsigned short* __restrict__ Ointra,
                                                         unsigned short* __restrict__ Tt) {
  const int bhc = blockIdx.x;
  const int c = bhc & 63, bh = bhc >> 6;
  const int h = bh & 7, b = bh >> 3;
  const int tid = threadIdx.x;
  __shared__ __align__(16) unsigned short Qb[4096], Kb[4096];
  __shared__ __align__(16) unsigned short Vt[64 * TS], Ht[64 * TS];
  __shared__ float lamF[4096];
  __shared__ float rnF[64];
  const long rowbase = ((long)(b * 4096 + c * 64)) * 2048;
  const int hoff = h * 64;

  if (tid < 64) rnF[tid] = 0.f;
  __syncthreads();

  // cooperative tile load (row t = u>>3, 16B part p = u&7);
  // sigmoid applied in flight -> lamF; V transposed into Vt; k ssq via LDS atomics
  #pragma unroll
  for (int chunk = 0; chunk < 2; ++chunk) {
    int u = chunk * 256 + tid;
    int t = u >> 3, p = u & 7;
    long g = rowbase + (long)t * 2048 + hoff + p * 8;
    uint4 q4 = *(const uint4*)(Cb + g);
    uint4 k4 = *(const uint4*)(Cb + g + 512);
    uint4 v4 = *(const uint4*)(Cb + g + 1024);
    uint4 a4 = *(const uint4*)(Cb + g + 1536);
    *(uint4*)&Qb[u * 8] = q4;
    *(uint4*)&Kb[u * 8] = k4;
    const unsigned short* vs = (const unsigned short*)&v4;
    #pragma unroll
    for (int j = 0; j < 8; ++j) Vt[(p * 8 + j) * TS + t] = vs[j];
    const unsigned short* as_ = (const unsigned short*)&a4;
    #pragma unroll
    for (int j = 0; j < 8; ++j) {
      float z = bf2f(as_[j]) + ba[hoff + p * 8 + j];
      lamF[t * 64 + p * 8 + j] = 1.f / (1.f + __expf(-z));
    }
    const unsigned short* ks = (const unsigned short*)&k4;
    float ssq = 0.f;
    #pragma unroll
    for (int j = 0; j < 8; ++j) { float kv = bf2f(ks[j]); ssq += kv * kv; }
    atomicAdd(&rnF[t], ssq);
  }
  __syncthreads();

  // wave0: cumprod per channel d (in-place) + Dvec; wave1: finalize rn
  if (tid < 64) {
    int d = tid; float cum = 1.f;
    #pragma unroll
    for (int t = 0; t < 64; ++t) { cum *= lamF[t * 64 + d]; lamF[t * 64 + d] = cum; }
    Dvec[(long)bhc * 64 + d] = cum;
  } else if (tid < 128) {
    int t = tid - 64;
    rnF[t] = 1.f / fmaxf(sqrtf(rnF[t]), 1e-12f);
  }
  __syncthreads();

  // transform in LDS: q~ = q*lam (row-major); k~ = kn/lam (row-major);
  // khat = kn*lend/lam transposed into Ht[d][t]
  {
    const int d = tid & 63;
    const float lend = lamF[63 * 64 + d];
    #pragma unroll
    for (int j = 0; j < 16; ++j) {
      int e = j * 256 + tid;
      int t = e >> 6;                 // wave-uniform
      float lam = lamF[e];
      float rl = 1.f / lam;
      float kn = bf2f(Kb[e]) * rnF[t];
      Qb[e] = f2bf(bf2f(Qb[e]) * lam);
      Kb[e] = f2bf(kn * rl);
      Ht[d * TS + t] = f2bf(kn * lend * rl);
    }
  }
  __syncthreads();

  // write qt (coalesced uint4 from transformed Qb)
  {
    const long obase = (long)bhc * 4096;
    uint4* gq = (uint4*)(qt + obase);
    const uint4* lq = (const uint4*)Qb;
    gq[tid] = lq[tid]; gq[tid + 256] = lq[tid + 256];
  }

  const long base = (long)bhc * 4096;
  const int wave = tid >> 6, lane = tid & 63, quad = lane >> 4, l16 = lane & 15;
  const int mrow = wave * 16 + l16;
  unsigned short* Ps = (unsigned short*)lamF;   // lamF dead after transform

  // P = q~ k~^T (contraction over d), causal mask -> LDS bf16
  {
    short8 a0 = *(const short8*)&Qb[mrow * 64 + quad * 8];
    short8 a1 = *(const short8*)&Qb[mrow * 64 + 32 + quad * 8];
    #pragma unroll
    for (int nt = 0; nt < 4; ++nt) {
      short8 b0 = *(const short8*)&Kb[(nt * 16 + l16) * 64 + quad * 8];
      short8 b1 = *(const short8*)&Kb[(nt * 16 + l16) * 64 + 32 + quad * 8];
      f32x4 acc = (f32x4){0.f, 0.f, 0.f, 0.f};
      acc = __builtin_amdgcn_mfma_f32_16x16x32_bf16(a0, b0, acc, 0, 0, 0);
      acc = __builtin_amdgcn_mfma_f32_16x16x32_bf16(a1, b1, acc, 0, 0, 0);
      #pragma unroll
      for (int r = 0; r < 4; ++r) {
        int t = wave * 16 + quad * 4 + r, u = nt * 16 + l16;
        Ps[t * 64 + u] = (u <= t) ? f2bf(acc[r]) : (unsigned short)0;
      }
    }
  }
  // O_intra[t][i] = sum_u P[t][u] * V[u][i]: A = P rows t (k=u), B = Vt rows i (k=u)
  {
    short8 a0 = *(const short8*)&Ps[mrow * 64 + quad * 8];
    short8 a1 = *(const short8*)&Ps[mrow * 64 + 32 + quad * 8];
    #pragma unroll
    for (int nt = 0; nt < 4; ++nt) {
      short8 b0 = *(const short8*)&Vt[(nt * 16 + l16) * TS + quad * 8];
      short8 b1 = *(const short8*)&Vt[(nt * 16 + l16) * TS + 32 + quad * 8];
      f32x4 acc = (f32x4){0.f, 0.f, 0.f, 0.f};
      acc = __builtin_amdgcn_mfma_f32_16x16x32_bf16(a0, b0, acc, 0, 0, 0);
      acc = __builtin_amdgcn_mfma_f32_16x16x32_bf16(a1, b1, acc, 0, 0, 0);
      #pragma unroll
      for (int r = 0; r < 4; ++r) {
        int t = wave * 16 + quad * 4 + r, i = nt * 16 + l16;
        Ointra[base + t * 64 + i] = f2bf(acc[r]);
      }
    }
  }
  // Tt[i][j] = sum_t V^T[i][t] * Khat^T[j][t]: A = Vt rows i, B = Ht rows j
  {
    short8 a0 = *(const short8*)&Vt[mrow * TS + quad * 8];
    short8 a1 = *(const short8*)&Vt[mrow * TS + 32 + quad * 8];
    #pragma unroll
    for (int nt = 0; nt < 4; ++nt) {
      short8 b0 = *(const short8*)&Ht[(nt * 16 + l16) * TS + quad * 8];
      short8 b1 = *(const short8*)&Ht[(nt * 16 + l16) * TS + 32 + quad * 8];
      f32x4 acc = (f32x4){0.f, 0.f, 0.f, 0.f};
      acc = __builtin_amdgcn_mfma_f32_16x16x32_bf16(a0, b0, acc, 0, 0, 0);
      acc = __builtin_amdgcn_mfma_f32_16x16x32_bf16(a1, b1, acc, 0, 0, 0);
      #pragma unroll
      for (int r = 0; r < 4; ++r) {
        int i = wave * 16 + quad * 4 + r, j = nt * 16 + l16;
        Tt[base + i * 64 + j] = f2bf(acc[r]);
      }
    }
  }
}

// ---------------- K5: chunk-state scan, element-parallel ---------------------
__global__ __launch_bounds__(256) void scan_kernel(const unsigned short* __restrict__ Tt,
                                                   const float* __restrict__ Dvec,
                                                   unsigned short* __restrict__ Sst) {
  const int bh = blockIdx.x;
  const int e = blockIdx.y * 256 + threadIdx.x;
  const int j = e & 63;
  float S = 0.f;
  for (int c = 0; c < 64; ++c) {
    const long idx = ((long)(bh * 64 + c)) * 4096 + e;
    const float dj = Dvec[((long)(bh * 64 + c)) * 64 + j];
    Sst[idx] = f2bf(S);                 // state BEFORE chunk c
    S = dj * S + bf2f(Tt[idx]);
  }
}

// ---------------- K6: O = O_intra + q~ @ S_prev, pack to [tok][h*64+i] bf16 --
__global__ __launch_bounds__(256) void combine_kernel(const unsigned short* __restrict__ qt,
                                                      const unsigned short* __restrict__ Sst,
                                                      const unsigned short* __restrict__ Ointra,
                                                      unsigned short* __restrict__ O) {
  const int bhc = blockIdx.x;
  const int c = bhc & 63, bh = bhc >> 6;
  const int h = bh & 7, b = bh >> 3;
  const long base = (long)bhc * 4096;
  __shared__ __align__(16) unsigned short Qs[4096], Sb[4096];
  const int tid = threadIdx.x;
  {
    const uint4* gq = (const uint4*)(qt + base);  uint4* lq = (uint4*)Qs;
    const uint4* gs = (const uint4*)(Sst + base); uint4* ls = (uint4*)Sb;
    lq[tid] = gq[tid]; lq[tid + 256] = gq[tid + 256];
    ls[tid] = gs[tid]; ls[tid + 256] = gs[tid + 256];
  }
  __syncthreads();
  const int wave = tid >> 6, lane = tid & 63, quad = lane >> 4, l16 = lane & 15;
  const int mrow = wave * 16 + l16;
  short8 a0 = *(const short8*)&Qs[mrow * 64 + quad * 8];
  short8 a1 = *(const short8*)&Qs[mrow * 64 + 32 + quad * 8];
  #pragma unroll
  for (int nt = 0; nt < 4; ++nt) {
    f32x4 acc;
    #pragma unroll
    for (int r = 0; r < 4; ++r) {
      int t = wave * 16 + quad * 4 + r, i = nt * 16 + l16;
      acc[r] = bf2f(Ointra[base + t * 64 + i]);
    }
    short8 b0 = *(const short8*)&Sb[(nt * 16 + l16) * 64 + quad * 8];
    short8 b1 = *(const short8*)&Sb[(nt * 16 + l16) * 64 + 32 + quad * 8];
    acc = __builtin_amdgcn_mfma_f32_16x16x32_bf16(a0, b0, acc, 0, 0, 0);
    acc = __builtin_amdgcn_mfma_f32_16x16x32_bf16(a1, b1, acc, 0, 0, 0);
    #pragma unroll
    for (int r = 0; r < 4; ++r) {
      int t = wave * 16 + quad * 4 + r, i = nt * 16 + l16;
      O[((long)(b * 4096 + c * 64 + t)) * 512 + h * 64 + i] = f2bf(acc[r]);
    }
  }
}

// ---------------- host ----------------
// Workspace layout (KB offsets), total 153088 KB, lifetime-aliased:
//   0       Wt     4096 KB   (whole call)
//   4096    Wot    1024 KB
//   5120    Dvec   512 KB
//   5632    qt     16384 KB  (prep_intra -> combine)
//   22016   Ttb    16384 KB  (prep_intra -> scan)
//   38400   Sst    16384 KB  (scan -> combine)
//   54784   xn     32768 KB  (ln -> gemm1); reused after gemm1:
//             Ointra @54784 (16384 KB, prep_intra -> combine)
//             Ob     @71168 (16384 KB, combine -> gemm2)
//   87552   Cb     65536 KB  (gemm1 -> prep_intra)
extern "C" void kernel_launch(void* const* d_in, const int* in_sizes, int n_in,
                              void* d_out, int out_size, void* d_ws, size_t ws_size,
                              hipStream_t stream) {
  const float* x     = (const float*)d_in[0];
  const float* Wq    = (const float*)d_in[1];
  const float* Wk    = (const float*)d_in[2];
  const float* Wv    = (const float*)d_in[3];
  const float* Wa    = (const float*)d_in[4];
  const float* ba    = (const float*)d_in[5];
  const float* Wo    = (const float*)d_in[6];
  const float* gamma = (const float*)d_in[7];
  const float* beta  = (const float*)d_in[8];
  float* out = (float*)d_out;

  char* ws = (char*)d_ws;
  const size_t KB = 1024;
  unsigned short* Wt     = (unsigned short*)(ws + 0 * KB);
  unsigned short* Wot    = (unsigned short*)(ws + 4096 * KB);
  float*          Dvec   = (float*)         (ws + 5120 * KB);
  unsigned short* qt     = (unsigned short*)(ws + 5632 * KB);
  unsigned short* Ttb    = (unsigned short*)(ws + 22016 * KB);
  unsigned short* Sst    = (unsigned short*)(ws + 38400 * KB);
  unsigned short* xn     = (unsigned short*)(ws + 54784 * KB);
  unsigned short* Ointra = (unsigned short*)(ws + 54784 * KB);  // aliases xn (dead after gemm1)
  unsigned short* Ob     = (unsigned short*)(ws + 71168 * KB);  // aliases xn tail (dead)
  unsigned short* Cb     = (unsigned short*)(ws + 87552 * KB);

  transpose4_bf16<<<dim3(16, 32, 4), 256, 0, stream>>>(Wq, Wk, Wv, Wa, Wt);
  transpose_bf16<<<dim3(32, 16), 256, 0, stream>>>(Wo, Wot, 512, 1024);
  ln_kernel<<<NTOK, 256, 0, stream>>>(x, gamma, beta, xn);
  gemm_bt<0><<<dim3(NTOK / 128, 2048 / 128), 256, 0, stream>>>(xn, Wt, Cb, nullptr, nullptr, NTOK, 2048, 1024);
  prep_intra_kernel<<<NBHC, 256, 0, stream>>>(Cb, ba, qt, Dvec, Ointra, Ttb);
  scan_kernel<<<dim3(32, 16), 256, 0, stream>>>(Ttb, Dvec, Sst);
  combine_kernel<<<NBHC, 256, 0, stream>>>(qt, Sst, Ointra, Ob);
  gemm_bt<1><<<dim3(NTOK / 128, 1024 / 128), 256, 0, stream>>>(Ob, Wot, nullptr, out, x, NTOK, 1024, 512);
}

// Round 6
// 310.995 us; speedup vs baseline: 1.2706x; 1.0751x over previous
//
#include <hip/hip_runtime.h>
#include <stdint.h>

#define NTOK   16384      // B*T = 4*4096
#define DM     1024
#define DI     512
#define NH     8
#define DH     64
#define CHUNK  64
#define NCH    64         // T / CHUNK
#define NBHC   2048       // B*H*NCH

using short8 = __attribute__((ext_vector_type(8))) short;
using f32x4  = __attribute__((ext_vector_type(4))) float;

__device__ __forceinline__ unsigned short f2bf(float f) {
  union { float f; unsigned int u; } x; x.f = f;
  unsigned int u = x.u;
  return (unsigned short)((u + 0x7fffu + ((u >> 16) & 1u)) >> 16);
}
__device__ __forceinline__ float bf2f(unsigned short h) {
  union { unsigned int u; float f; } x; x.u = ((unsigned int)h) << 16; return x.f;
}

typedef const __attribute__((address_space(1))) void* gp1_t;
typedef __attribute__((address_space(3))) void* lp3_t;
__device__ __forceinline__ void gload_lds16(const void* g, void* l) {
  __builtin_amdgcn_global_load_lds((gp1_t)g, (lp3_t)l, 16, 0, 0);
}

// ---------------- K0a: 4x fused fp32 -> bf16 transpose (1024x512 each) -------
__global__ __launch_bounds__(256) void transpose4_bf16(const float* __restrict__ Wq,
                                                       const float* __restrict__ Wk,
                                                       const float* __restrict__ Wv,
                                                       const float* __restrict__ Wa,
                                                       unsigned short* __restrict__ out) {
  const int z = blockIdx.z;
  const float* in = (z == 0) ? Wq : (z == 1) ? Wk : (z == 2) ? Wv : Wa;
  unsigned short* o = out + (size_t)z * 512 * 1024;
  __shared__ float tile[32][33];
  int bx = blockIdx.x * 32;           // col base (output row base), C=512
  int by = blockIdx.y * 32;           // row base, R=1024
  int tx = threadIdx.x & 31, ty = threadIdx.x >> 5;
  #pragma unroll
  for (int r = ty; r < 32; r += 8) tile[r][tx] = in[(long)(by + r) * 512 + bx + tx];
  __syncthreads();
  #pragma unroll
  for (int r = ty; r < 32; r += 8) o[(long)(bx + r) * 1024 + by + tx] = f2bf(tile[tx][r]);
}

// ---------------- K0b: Wo transpose (512x1024 -> 1024x512) -------------------
__global__ __launch_bounds__(256) void transpose_bf16(const float* __restrict__ in,
                                                      unsigned short* __restrict__ out,
                                                      int R, int C) {
  __shared__ float tile[32][33];
  int bx = blockIdx.x * 32;
  int by = blockIdx.y * 32;
  int tx = threadIdx.x & 31, ty = threadIdx.x >> 5;
  #pragma unroll
  for (int r = ty; r < 32; r += 8) tile[r][tx] = in[(long)(by + r) * C + bx + tx];
  __syncthreads();
  #pragma unroll
  for (int r = ty; r < 32; r += 8) out[(long)(bx + r) * R + by + tx] = f2bf(tile[tx][r]);
}

// ---------------- K1: LayerNorm -> bf16 --------------------------------------
__global__ __launch_bounds__(256) void ln_kernel(const float* __restrict__ x,
                                                 const float* __restrict__ gamma,
                                                 const float* __restrict__ beta,
                                                 unsigned short* __restrict__ xn) {
  const int row = blockIdx.x, tid = threadIdx.x;
  float4 v = ((const float4*)(x + (long)row * DM))[tid];
  float s  = v.x + v.y + v.z + v.w;
  float ss = v.x * v.x + v.y * v.y + v.z * v.z + v.w * v.w;
  #pragma unroll
  for (int off = 32; off > 0; off >>= 1) { s += __shfl_down(s, off); ss += __shfl_down(ss, off); }
  __shared__ float rs_[4], rss_[4];
  int wave = tid >> 6, lane = tid & 63;
  if (lane == 0) { rs_[wave] = s; rss_[wave] = ss; }
  __syncthreads();
  s  = rs_[0] + rs_[1] + rs_[2] + rs_[3];
  ss = rss_[0] + rss_[1] + rss_[2] + rss_[3];
  float mu   = s * (1.f / DM);
  float var  = ss * (1.f / DM) - mu * mu;
  float rstd = rsqrtf(var + 1e-5f);
  int idx = tid * 4;
  float xv[4] = {v.x, v.y, v.z, v.w};
  unsigned short o[4];
  #pragma unroll
  for (int j = 0; j < 4; ++j) o[j] = f2bf((xv[j] - mu) * rstd * gamma[idx + j] + beta[idx + j]);
  uint2 pk; pk.x = (unsigned)o[0] | ((unsigned)o[1] << 16); pk.y = (unsigned)o[2] | ((unsigned)o[3] << 16);
  *(uint2*)(xn + (long)row * DM + idx) = pk;
}

// ---------------- GEMM: C[M][N] = A(bf16 MxK) * Bt(bf16 NxK)^T ---------------
// 256x128 tile, 512 threads (8 waves = 4 M-slots x 2 N-slots, 64x64 each).
// MODE 0: store bf16 to Cb.  MODE 1: store fp32 + residual to Cf.
// Epilogue repacks through LDS (reusing staging space) in two 128-row passes.
#define EPS 136   // epilogue LDS row stride (shorts): 272 B rows -> 16B-aligned b128
template <int MODE>
__global__ __launch_bounds__(512) void gemm_bt(const unsigned short* __restrict__ A,
                                               const unsigned short* __restrict__ Bt,
                                               unsigned short* __restrict__ Cb,
                                               float* __restrict__ Cf,
                                               const float* __restrict__ resid,
                                               int M, int N, int K) {
  __shared__ __align__(16) unsigned short smem[128 * EPS];  // stage 24576 B | epi 34816 B
  unsigned short* As = smem;          // 256*32
  unsigned short* Bs = smem + 8192;   // 128*32
  const int tid = threadIdx.x;
  const int wave = tid >> 6, lane = tid & 63;
  const int quad = lane >> 4, l16 = lane & 15;

  // block swizzle: groups of 4 M-tiles x all N-tiles
  const int Nt = gridDim.y;
  int id = blockIdx.x + blockIdx.y * gridDim.x;
  int group = id / (4 * Nt);
  int rem = id - group * (4 * Nt);
  const int m0 = (group * 4 + (rem & 3)) * 256;
  const int n0 = (rem >> 2) * 128;
  const int wm = (wave & 3) * 64, wn = (wave >> 2) * 64;

  const int r4 = tid >> 2, p4 = (tid & 3) * 8;
  const unsigned short* Ag0 = A + (long)(m0 + r4) * K + p4;
  const unsigned short* Ag1 = A + (long)(m0 + 128 + r4) * K + p4;
  const unsigned short* Bg0 = Bt + (long)(n0 + r4) * K + p4;

  f32x4 acc[4][4];
  #pragma unroll
  for (int i = 0; i < 4; ++i)
    #pragma unroll
    for (int j = 0; j < 4; ++j) acc[i][j] = (f32x4){0.f, 0.f, 0.f, 0.f};

  for (int k0 = 0; k0 < K; k0 += 32) {
    __syncthreads();
    gload_lds16(Ag0 + k0, &As[tid * 8]);
    gload_lds16(Ag1 + k0, &As[(tid + 512) * 8]);
    gload_lds16(Bg0 + k0, &Bs[tid * 8]);
    __syncthreads();
    short8 a[4], b[4];
    #pragma unroll
    for (int mt = 0; mt < 4; ++mt) a[mt] = *(const short8*)&As[(wm + mt * 16 + l16) * 32 + quad * 8];
    #pragma unroll
    for (int nt = 0; nt < 4; ++nt) b[nt] = *(const short8*)&Bs[(wn + nt * 16 + l16) * 32 + quad * 8];
    #pragma unroll
    for (int mt = 0; mt < 4; ++mt)
      #pragma unroll
      for (int nt = 0; nt < 4; ++nt)
        acc[mt][nt] = __builtin_amdgcn_mfma_f32_16x16x32_bf16(a[mt], b[nt], acc[mt][nt], 0, 0, 0);
  }
  // ---- epilogue: two 128-row passes through LDS, coalesced global stores ----
  unsigned short* epi = smem;
  const int mypass = (wave & 3) >> 1;         // wm in {0,64} -> pass 0; {128,192} -> pass 1
  const int rloc = ((wave & 1) * 64);         // row base within the pass
  #pragma unroll
  for (int h = 0; h < 2; ++h) {
    __syncthreads();                          // smem free (K-loop reads / prior stores done)
    if (mypass == h) {
      #pragma unroll
      for (int mt = 0; mt < 4; ++mt)
        #pragma unroll
        for (int nt = 0; nt < 4; ++nt)
          #pragma unroll
          for (int r = 0; r < 4; ++r)
            epi[(rloc + mt * 16 + quad * 4 + r) * EPS + wn + nt * 16 + l16] = f2bf(acc[mt][nt][r]);
    }
    __syncthreads();
    if (MODE == 0) {
      #pragma unroll
      for (int i = tid; i < 2048; i += 512) {
        int row = i >> 4, cc = (i & 15) * 8;
        uint4 v = *(const uint4*)&epi[row * EPS + cc];
        *(uint4*)&Cb[(long)(m0 + h * 128 + row) * N + n0 + cc] = v;
      }
    } else {
      #pragma unroll
      for (int i = tid; i < 4096; i += 512) {
        int row = i >> 5, cc = (i & 31) * 4;
        long g = (long)(m0 + h * 128 + row) * N + n0 + cc;
        float4 rv = *(const float4*)&resid[g];
        uint2 pv = *(const uint2*)&epi[row * EPS + cc];
        float4 ov;
        ov.x = bf2f((unsigned short)(pv.x & 0xffffu)) + rv.x;
        ov.y = bf2f((unsigned short)(pv.x >> 16))     + rv.y;
        ov.z = bf2f((unsigned short)(pv.y & 0xffffu)) + rv.z;
        ov.w = bf2f((unsigned short)(pv.y >> 16))     + rv.w;
        *(float4*)&Cf[g] = ov;
      }
    }
  }
}

// ---------------- K3: fused per-chunk prep + intra-chunk attention -----------
// Cb row layout (bf16): [q 0..511 | k 512..1023 | v 1024..1535 | alog 1536..2047]
// LDS: Qb,Kb row-major [t][d]; Vt,Ht transposed [d][t] stride 72;
// lamF fp32 (sigmoid applied at load); Ps overlays lamF after transform.
#define TS 72
__global__ __launch_bounds__(256) void prep_intra_kernel(const unsigned short* __restrict__ Cb,
                                                         const float* __restrict__ ba,
                                                         unsigned short* __restrict__ qt,
                                                         float* __restrict__ Dvec,
                                                         unsigned short* __restrict__ Ointra,
                                                         unsigned short* __restrict__ Tt) {
  const int bhc = blockIdx.x;
  const int c = bhc & 63, bh = bhc >> 6;
  const int h = bh & 7, b = bh >> 3;
  const int tid = threadIdx.x;
  __shared__ __align__(16) unsigned short Qb[4096], Kb[4096];
  __shared__ __align__(16) unsigned short Vt[64 * TS], Ht[64 * TS];
  __shared__ float lamF[4096];
  __shared__ float rnF[64];
  const long rowbase = ((long)(b * 4096 + c * 64)) * 2048;
  const int hoff = h * 64;

  if (tid < 64) rnF[tid] = 0.f;
  __syncthreads();

  #pragma unroll
  for (int chunk = 0; chunk < 2; ++chunk) {
    int u = chunk * 256 + tid;
    int t = u >> 3, p = u & 7;
    long g = rowbase + (long)t * 2048 + hoff + p * 8;
    uint4 q4 = *(const uint4*)(Cb + g);
    uint4 k4 = *(const uint4*)(Cb + g + 512);
    uint4 v4 = *(const uint4*)(Cb + g + 1024);
    uint4 a4 = *(const uint4*)(Cb + g + 1536);
    *(uint4*)&Qb[u * 8] = q4;
    *(uint4*)&Kb[u * 8] = k4;
    const unsigned short* vs = (const unsigned short*)&v4;
    #pragma unroll
    for (int j = 0; j < 8; ++j) Vt[(p * 8 + j) * TS + t] = vs[j];
    const unsigned short* as_ = (const unsigned short*)&a4;
    #pragma unroll
    for (int j = 0; j < 8; ++j) {
      float z = bf2f(as_[j]) + ba[hoff + p * 8 + j];
      lamF[t * 64 + p * 8 + j] = 1.f / (1.f + __expf(-z));
    }
    const unsigned short* ks = (const unsigned short*)&k4;
    float ssq = 0.f;
    #pragma unroll
    for (int j = 0; j < 8; ++j) { float kv = bf2f(ks[j]); ssq += kv * kv; }
    atomicAdd(&rnF[t], ssq);
  }
  __syncthreads();

  if (tid < 64) {
    int d = tid; float cum = 1.f;
    #pragma unroll
    for (int t = 0; t < 64; ++t) { cum *= lamF[t * 64 + d]; lamF[t * 64 + d] = cum; }
    Dvec[(long)bhc * 64 + d] = cum;
  } else if (tid < 128) {
    int t = tid - 64;
    rnF[t] = 1.f / fmaxf(sqrtf(rnF[t]), 1e-12f);
  }
  __syncthreads();

  {
    const int d = tid & 63;
    const float lend = lamF[63 * 64 + d];
    #pragma unroll
    for (int j = 0; j < 16; ++j) {
      int e = j * 256 + tid;
      int t = e >> 6;                 // wave-uniform
      float lam = lamF[e];
      float rl = 1.f / lam;
      float kn = bf2f(Kb[e]) * rnF[t];
      Qb[e] = f2bf(bf2f(Qb[e]) * lam);
      Kb[e] = f2bf(kn * rl);
      Ht[d * TS + t] = f2bf(kn * lend * rl);
    }
  }
  __syncthreads();

  {
    const long obase = (long)bhc * 4096;
    uint4* gq = (uint4*)(qt + obase);
    const uint4* lq = (const uint4*)Qb;
    gq[tid] = lq[tid]; gq[tid + 256] = lq[tid + 256];
  }

  const long base = (long)bhc * 4096;
  const int wave = tid >> 6, lane = tid & 63, quad = lane >> 4, l16 = lane & 15;
  const int mrow = wave * 16 + l16;
  unsigned short* Ps = (unsigned short*)lamF;   // lamF dead after transform

  {
    short8 a0 = *(const short8*)&Qb[mrow * 64 + quad * 8];
    short8 a1 = *(const short8*)&Qb[mrow * 64 + 32 + quad * 8];
    #pragma unroll
    for (int nt = 0; nt < 4; ++nt) {
      short8 b0 = *(const short8*)&Kb[(nt * 16 + l16) * 64 + quad * 8];
      short8 b1 = *(const short8*)&Kb[(nt * 16 + l16) * 64 + 32 + quad * 8];
      f32x4 acc = (f32x4){0.f, 0.f, 0.f, 0.f};
      acc = __builtin_amdgcn_mfma_f32_16x16x32_bf16(a0, b0, acc, 0, 0, 0);
      acc = __builtin_amdgcn_mfma_f32_16x16x32_bf16(a1, b1, acc, 0, 0, 0);
      #pragma unroll
      for (int r = 0; r < 4; ++r) {
        int t = wave * 16 + quad * 4 + r, u = nt * 16 + l16;
        Ps[t * 64 + u] = (u <= t) ? f2bf(acc[r]) : (unsigned short)0;
      }
    }
  }
  {
    short8 a0 = *(const short8*)&Ps[mrow * 64 + quad * 8];
    short8 a1 = *(const short8*)&Ps[mrow * 64 + 32 + quad * 8];
    #pragma unroll
    for (int nt = 0; nt < 4; ++nt) {
      short8 b0 = *(const short8*)&Vt[(nt * 16 + l16) * TS + quad * 8];
      short8 b1 = *(const short8*)&Vt[(nt * 16 + l16) * TS + 32 + quad * 8];
      f32x4 acc = (f32x4){0.f, 0.f, 0.f, 0.f};
      acc = __builtin_amdgcn_mfma_f32_16x16x32_bf16(a0, b0, acc, 0, 0, 0);
      acc = __builtin_amdgcn_mfma_f32_16x16x32_bf16(a1, b1, acc, 0, 0, 0);
      #pragma unroll
      for (int r = 0; r < 4; ++r) {
        int t = wave * 16 + quad * 4 + r, i = nt * 16 + l16;
        Ointra[base + t * 64 + i] = f2bf(acc[r]);
      }
    }
  }
  {
    short8 a0 = *(const short8*)&Vt[mrow * TS + quad * 8];
    short8 a1 = *(const short8*)&Vt[mrow * TS + 32 + quad * 8];
    #pragma unroll
    for (int nt = 0; nt < 4; ++nt) {
      short8 b0 = *(const short8*)&Ht[(nt * 16 + l16) * TS + quad * 8];
      short8 b1 = *(const short8*)&Ht[(nt * 16 + l16) * TS + 32 + quad * 8];
      f32x4 acc = (f32x4){0.f, 0.f, 0.f, 0.f};
      acc = __builtin_amdgcn_mfma_f32_16x16x32_bf16(a0, b0, acc, 0, 0, 0);
      acc = __builtin_amdgcn_mfma_f32_16x16x32_bf16(a1, b1, acc, 0, 0, 0);
      #pragma unroll
      for (int r = 0; r < 4; ++r) {
        int i = wave * 16 + quad * 4 + r, j = nt * 16 + l16;
        Tt[base + i * 64 + j] = f2bf(acc[r]);
      }
    }
  }
}

// ---------------- K5: chunk-state scan, element-parallel ---------------------
__global__ __launch_bounds__(256) void scan_kernel(const unsigned short* __restrict__ Tt,
                                                   const float* __restrict__ Dvec,
                                                   unsigned short* __restrict__ Sst) {
  const int bh = blockIdx.x;
  const int e = blockIdx.y * 256 + threadIdx.x;
  const int j = e & 63;
  float S = 0.f;
  for (int c = 0; c < 64; ++c) {
    const long idx = ((long)(bh * 64 + c)) * 4096 + e;
    const float dj = Dvec[((long)(bh * 64 + c)) * 64 + j];
    Sst[idx] = f2bf(S);                 // state BEFORE chunk c
    S = dj * S + bf2f(Tt[idx]);
  }
}

// ---------------- K6: O = O_intra + q~ @ S_prev, pack to [tok][h*64+i] bf16 --
__global__ __launch_bounds__(256) void combine_kernel(const unsigned short* __restrict__ qt,
                                                      const unsigned short* __restrict__ Sst,
                                                      const unsigned short* __restrict__ Ointra,
                                                      unsigned short* __restrict__ O) {
  const int bhc = blockIdx.x;
  const int c = bhc & 63, bh = bhc >> 6;
  const int h = bh & 7, b = bh >> 3;
  const long base = (long)bhc * 4096;
  __shared__ __align__(16) unsigned short Qs[4096], Sb[4096];
  const int tid = threadIdx.x;
  {
    const uint4* gq = (const uint4*)(qt + base);  uint4* lq = (uint4*)Qs;
    const uint4* gs = (const uint4*)(Sst + base); uint4* ls = (uint4*)Sb;
    lq[tid] = gq[tid]; lq[tid + 256] = gq[tid + 256];
    ls[tid] = gs[tid]; ls[tid + 256] = gs[tid + 256];
  }
  __syncthreads();
  const int wave = tid >> 6, lane = tid & 63, quad = lane >> 4, l16 = lane & 15;
  const int mrow = wave * 16 + l16;
  short8 a0 = *(const short8*)&Qs[mrow * 64 + quad * 8];
  short8 a1 = *(const short8*)&Qs[mrow * 64 + 32 + quad * 8];
  #pragma unroll
  for (int nt = 0; nt < 4; ++nt) {
    f32x4 acc;
    #pragma unroll
    for (int r = 0; r < 4; ++r) {
      int t = wave * 16 + quad * 4 + r, i = nt * 16 + l16;
      acc[r] = bf2f(Ointra[base + t * 64 + i]);
    }
    short8 b0 = *(const short8*)&Sb[(nt * 16 + l16) * 64 + quad * 8];
    short8 b1 = *(const short8*)&Sb[(nt * 16 + l16) * 64 + 32 + quad * 8];
    acc = __builtin_amdgcn_mfma_f32_16x16x32_bf16(a0, b0, acc, 0, 0, 0);
    acc = __builtin_amdgcn_mfma_f32_16x16x32_bf16(a1, b1, acc, 0, 0, 0);
    #pragma unroll
    for (int r = 0; r < 4; ++r) {
      int t = wave * 16 + quad * 4 + r, i = nt * 16 + l16;
      O[((long)(b * 4096 + c * 64 + t)) * 512 + h * 64 + i] = f2bf(acc[r]);
    }
  }
}

// ---------------- host ----------------
// Workspace layout (KB offsets), total 153088 KB, lifetime-aliased:
//   0       Wt     4096 KB   (whole call)
//   4096    Wot    1024 KB
//   5120    Dvec   512 KB
//   5632    qt     16384 KB  (prep_intra -> combine)
//   22016   Ttb    16384 KB  (prep_intra -> scan)
//   38400   Sst    16384 KB  (scan -> combine)
//   54784   xn     32768 KB  (ln -> gemm1); reused after gemm1:
//             Ointra @54784 (16384 KB), Ob @71168 (16384 KB)
//   87552   Cb     65536 KB  (gemm1 -> prep_intra)
extern "C" void kernel_launch(void* const* d_in, const int* in_sizes, int n_in,
                              void* d_out, int out_size, void* d_ws, size_t ws_size,
                              hipStream_t stream) {
  const float* x     = (const float*)d_in[0];
  const float* Wq    = (const float*)d_in[1];
  const float* Wk    = (const float*)d_in[2];
  const float* Wv    = (const float*)d_in[3];
  const float* Wa    = (const float*)d_in[4];
  const float* ba    = (const float*)d_in[5];
  const float* Wo    = (const float*)d_in[6];
  const float* gamma = (const float*)d_in[7];
  const float* beta  = (const float*)d_in[8];
  float* out = (float*)d_out;

  char* ws = (char*)d_ws;
  const size_t KB = 1024;
  unsigned short* Wt     = (unsigned short*)(ws + 0 * KB);
  unsigned short* Wot    = (unsigned short*)(ws + 4096 * KB);
  float*          Dvec   = (float*)         (ws + 5120 * KB);
  unsigned short* qt     = (unsigned short*)(ws + 5632 * KB);
  unsigned short* Ttb    = (unsigned short*)(ws + 22016 * KB);
  unsigned short* Sst    = (unsigned short*)(ws + 38400 * KB);
  unsigned short* xn     = (unsigned short*)(ws + 54784 * KB);
  unsigned short* Ointra = (unsigned short*)(ws + 54784 * KB);  // aliases xn (dead after gemm1)
  unsigned short* Ob     = (unsigned short*)(ws + 71168 * KB);  // aliases xn tail (dead)
  unsigned short* Cb     = (unsigned short*)(ws + 87552 * KB);

  transpose4_bf16<<<dim3(16, 32, 4), 256, 0, stream>>>(Wq, Wk, Wv, Wa, Wt);
  transpose_bf16<<<dim3(32, 16), 256, 0, stream>>>(Wo, Wot, 512, 1024);
  ln_kernel<<<NTOK, 256, 0, stream>>>(x, gamma, beta, xn);
  gemm_bt<0><<<dim3(NTOK / 256, 2048 / 128), 512, 0, stream>>>(xn, Wt, Cb, nullptr, nullptr, NTOK, 2048, 1024);
  prep_intra_kernel<<<NBHC, 256, 0, stream>>>(Cb, ba, qt, Dvec, Ointra, Ttb);
  scan_kernel<<<dim3(32, 16), 256, 0, stream>>>(Ttb, Dvec, Sst);
  combine_kernel<<<NBHC, 256, 0, stream>>>(qt, Sst, Ointra, Ob);
  gemm_bt<1><<<dim3(NTOK / 256, 1024 / 128), 512, 0, stream>>>(Ob, Wot, nullptr, out, x, NTOK, 1024, 512);
}

// Round 7
// 305.836 us; speedup vs baseline: 1.2921x; 1.0169x over previous
//
#include <hip/hip_runtime.h>
#include <stdint.h>

#define NTOK   16384      // B*T = 4*4096
#define DM     1024
#define DI     512
#define NH     8
#define DH     64
#define CHUNK  64
#define NCH    64         // T / CHUNK
#define NBHC   2048       // B*H*NCH

using short8 = __attribute__((ext_vector_type(8))) short;
using f32x4  = __attribute__((ext_vector_type(4))) float;

__device__ __forceinline__ unsigned short f2bf(float f) {
  union { float f; unsigned int u; } x; x.f = f;
  unsigned int u = x.u;
  return (unsigned short)((u + 0x7fffu + ((u >> 16) & 1u)) >> 16);
}
__device__ __forceinline__ float bf2f(unsigned short h) {
  union { unsigned int u; float f; } x; x.u = ((unsigned int)h) << 16; return x.f;
}

typedef const __attribute__((address_space(1))) void* gp1_t;
typedef __attribute__((address_space(3))) void* lp3_t;
__device__ __forceinline__ void gload_lds16(const void* g, void* l) {
  __builtin_amdgcn_global_load_lds((gp1_t)g, (lp3_t)l, 16, 0, 0);
}

// ---------------- K0: fused init: LN (blocks 0..16383), W transposes ---------
// blocks [16384, 18432): Wq/Wk/Wv/Wa transpose (z = (id)>>9), 1024x512 -> 512x1024
// blocks [18432, 18944): Wo transpose, 512x1024 -> 1024x512
__global__ __launch_bounds__(256) void init_kernel(const float* __restrict__ x,
                                                   const float* __restrict__ gamma,
                                                   const float* __restrict__ beta,
                                                   const float* __restrict__ Wq,
                                                   const float* __restrict__ Wk,
                                                   const float* __restrict__ Wv,
                                                   const float* __restrict__ Wa,
                                                   const float* __restrict__ Wo,
                                                   unsigned short* __restrict__ xn,
                                                   unsigned short* __restrict__ Wt,
                                                   unsigned short* __restrict__ Wot) {
  const int blk = blockIdx.x, tid = threadIdx.x;
  __shared__ float tile[32][33];
  __shared__ float rs_[4], rss_[4];
  if (blk < NTOK) {
    const int row = blk;
    float4 v = ((const float4*)(x + (long)row * DM))[tid];
    float s  = v.x + v.y + v.z + v.w;
    float ss = v.x * v.x + v.y * v.y + v.z * v.z + v.w * v.w;
    #pragma unroll
    for (int off = 32; off > 0; off >>= 1) { s += __shfl_down(s, off); ss += __shfl_down(ss, off); }
    int wave = tid >> 6, lane = tid & 63;
    if (lane == 0) { rs_[wave] = s; rss_[wave] = ss; }
    __syncthreads();
    s  = rs_[0] + rs_[1] + rs_[2] + rs_[3];
    ss = rss_[0] + rss_[1] + rss_[2] + rss_[3];
    float mu   = s * (1.f / DM);
    float var  = ss * (1.f / DM) - mu * mu;
    float rstd = rsqrtf(var + 1e-5f);
    int idx = tid * 4;
    float xv[4] = {v.x, v.y, v.z, v.w};
    unsigned short o[4];
    #pragma unroll
    for (int j = 0; j < 4; ++j) o[j] = f2bf((xv[j] - mu) * rstd * gamma[idx + j] + beta[idx + j]);
    uint2 pk; pk.x = (unsigned)o[0] | ((unsigned)o[1] << 16); pk.y = (unsigned)o[2] | ((unsigned)o[3] << 16);
    *(uint2*)(xn + (long)row * DM + idx) = pk;
  } else if (blk < NTOK + 2048) {
    const int id = blk - NTOK;
    const int z = id >> 9, r9 = id & 511;
    const float* in = (z == 0) ? Wq : (z == 1) ? Wk : (z == 2) ? Wv : Wa;
    unsigned short* o = Wt + (size_t)z * 512 * 1024;
    int bx = (r9 & 15) * 32, by = (r9 >> 4) * 32;
    int tx = tid & 31, ty = tid >> 5;
    #pragma unroll
    for (int r = ty; r < 32; r += 8) tile[r][tx] = in[(long)(by + r) * 512 + bx + tx];
    __syncthreads();
    #pragma unroll
    for (int r = ty; r < 32; r += 8) o[(long)(bx + r) * 1024 + by + tx] = f2bf(tile[tx][r]);
  } else {
    const int id = blk - NTOK - 2048;
    int bx = (id & 31) * 32, by = (id >> 5) * 32;
    int tx = tid & 31, ty = tid >> 5;
    #pragma unroll
    for (int r = ty; r < 32; r += 8) tile[r][tx] = Wo[(long)(by + r) * 1024 + bx + tx];
    __syncthreads();
    #pragma unroll
    for (int r = ty; r < 32; r += 8) Wot[(long)(bx + r) * 512 + by + tx] = f2bf(tile[tx][r]);
  }
}

// ---------------- GEMM: C[M][N] = A(bf16 MxK) * Bt(bf16 NxK)^T ---------------
// 256x128 tile, 512 threads (8 waves = 4 M-slots x 2 N-slots, 64x64 each).
// MODE 0: store bf16 to Cb.  MODE 1: store fp32 + residual to Cf.
#define EPS 136   // epilogue LDS row stride (shorts)
template <int MODE>
__global__ __launch_bounds__(512) void gemm_bt(const unsigned short* __restrict__ A,
                                               const unsigned short* __restrict__ Bt,
                                               unsigned short* __restrict__ Cb,
                                               float* __restrict__ Cf,
                                               const float* __restrict__ resid,
                                               int M, int N, int K) {
  __shared__ __align__(16) unsigned short smem[128 * EPS];
  unsigned short* As = smem;          // 256*32
  unsigned short* Bs = smem + 8192;   // 128*32
  const int tid = threadIdx.x;
  const int wave = tid >> 6, lane = tid & 63;
  const int quad = lane >> 4, l16 = lane & 15;

  const int Nt = gridDim.y;
  int id = blockIdx.x + blockIdx.y * gridDim.x;
  int group = id / (4 * Nt);
  int rem = id - group * (4 * Nt);
  const int m0 = (group * 4 + (rem & 3)) * 256;
  const int n0 = (rem >> 2) * 128;
  const int wm = (wave & 3) * 64, wn = (wave >> 2) * 64;

  const int r4 = tid >> 2, p4 = (tid & 3) * 8;
  const unsigned short* Ag0 = A + (long)(m0 + r4) * K + p4;
  const unsigned short* Ag1 = A + (long)(m0 + 128 + r4) * K + p4;
  const unsigned short* Bg0 = Bt + (long)(n0 + r4) * K + p4;

  f32x4 acc[4][4];
  #pragma unroll
  for (int i = 0; i < 4; ++i)
    #pragma unroll
    for (int j = 0; j < 4; ++j) acc[i][j] = (f32x4){0.f, 0.f, 0.f, 0.f};

  for (int k0 = 0; k0 < K; k0 += 32) {
    __syncthreads();
    gload_lds16(Ag0 + k0, &As[tid * 8]);
    gload_lds16(Ag1 + k0, &As[(tid + 512) * 8]);
    gload_lds16(Bg0 + k0, &Bs[tid * 8]);
    __syncthreads();
    short8 a[4], b[4];
    #pragma unroll
    for (int mt = 0; mt < 4; ++mt) a[mt] = *(const short8*)&As[(wm + mt * 16 + l16) * 32 + quad * 8];
    #pragma unroll
    for (int nt = 0; nt < 4; ++nt) b[nt] = *(const short8*)&Bs[(wn + nt * 16 + l16) * 32 + quad * 8];
    #pragma unroll
    for (int mt = 0; mt < 4; ++mt)
      #pragma unroll
      for (int nt = 0; nt < 4; ++nt)
        acc[mt][nt] = __builtin_amdgcn_mfma_f32_16x16x32_bf16(a[mt], b[nt], acc[mt][nt], 0, 0, 0);
  }
  unsigned short* epi = smem;
  const int mypass = (wave & 3) >> 1;
  const int rloc = ((wave & 1) * 64);
  #pragma unroll
  for (int h = 0; h < 2; ++h) {
    __syncthreads();
    if (mypass == h) {
      #pragma unroll
      for (int mt = 0; mt < 4; ++mt)
        #pragma unroll
        for (int nt = 0; nt < 4; ++nt)
          #pragma unroll
          for (int r = 0; r < 4; ++r)
            epi[(rloc + mt * 16 + quad * 4 + r) * EPS + wn + nt * 16 + l16] = f2bf(acc[mt][nt][r]);
    }
    __syncthreads();
    if (MODE == 0) {
      #pragma unroll
      for (int i = tid; i < 2048; i += 512) {
        int row = i >> 4, cc = (i & 15) * 8;
        uint4 v = *(const uint4*)&epi[row * EPS + cc];
        *(uint4*)&Cb[(long)(m0 + h * 128 + row) * N + n0 + cc] = v;
      }
    } else {
      #pragma unroll
      for (int i = tid; i < 4096; i += 512) {
        int row = i >> 5, cc = (i & 31) * 4;
        long g = (long)(m0 + h * 128 + row) * N + n0 + cc;
        float4 rv = *(const float4*)&resid[g];
        uint2 pv = *(const uint2*)&epi[row * EPS + cc];
        float4 ov;
        ov.x = bf2f((unsigned short)(pv.x & 0xffffu)) + rv.x;
        ov.y = bf2f((unsigned short)(pv.x >> 16))     + rv.y;
        ov.z = bf2f((unsigned short)(pv.y & 0xffffu)) + rv.z;
        ov.w = bf2f((unsigned short)(pv.y >> 16))     + rv.w;
        *(float4*)&Cf[g] = ov;
      }
    }
  }
}

// ---------------- K3: fused per-chunk prep + intra-chunk attention -----------
// Cb row layout (bf16): [q | k | v | alog]. Transposes of V and K~ built via
// MFMA identity-transpose (no strided scalar LDS stores). Tt scaled by lend[j]
// in epilogue (khat never materialized). lamB bf16 (cumprod in fp32 regs).
#define TS 72
__global__ __launch_bounds__(256) void prep_intra_kernel(const unsigned short* __restrict__ Cb,
                                                         const float* __restrict__ ba,
                                                         unsigned short* __restrict__ qt,
                                                         float* __restrict__ Dvec,
                                                         unsigned short* __restrict__ Ointra,
                                                         unsigned short* __restrict__ Tt) {
  const int bhc = blockIdx.x;
  const int c = bhc & 63, bh = bhc >> 6;
  const int h = bh & 7, b = bh >> 3;
  const int tid = threadIdx.x;
  __shared__ __align__(16) unsigned short Qb[4096], Kb[4096], Vb[4096], lamB[4096];
  __shared__ __align__(16) unsigned short Vt[64 * TS], Kt[64 * TS];
  __shared__ float rnF[64], lendF[64];
  const long rowbase = ((long)(b * 4096 + c * 64)) * 2048;
  const int hoff = h * 64;

  if (tid < 64) rnF[tid] = 0.f;
  __syncthreads();

  // load: Q,K,V row-major; alpha = sigmoid(alog+ba) -> lamB bf16; k ssq
  #pragma unroll
  for (int chunk = 0; chunk < 2; ++chunk) {
    int u = chunk * 256 + tid;
    int t = u >> 3, p = u & 7;
    long g = rowbase + (long)t * 2048 + hoff + p * 8;
    uint4 q4 = *(const uint4*)(Cb + g);
    uint4 k4 = *(const uint4*)(Cb + g + 512);
    uint4 v4 = *(const uint4*)(Cb + g + 1024);
    uint4 a4 = *(const uint4*)(Cb + g + 1536);
    *(uint4*)&Qb[u * 8] = q4;
    *(uint4*)&Kb[u * 8] = k4;
    *(uint4*)&Vb[u * 8] = v4;
    const unsigned short* as_ = (const unsigned short*)&a4;
    unsigned short al[8];
    #pragma unroll
    for (int j = 0; j < 8; ++j) {
      float z = bf2f(as_[j]) + ba[hoff + p * 8 + j];
      al[j] = f2bf(1.f / (1.f + __expf(-z)));
    }
    uint4 pa;
    pa.x = (unsigned)al[0] | ((unsigned)al[1] << 16); pa.y = (unsigned)al[2] | ((unsigned)al[3] << 16);
    pa.z = (unsigned)al[4] | ((unsigned)al[5] << 16); pa.w = (unsigned)al[6] | ((unsigned)al[7] << 16);
    *(uint4*)&lamB[u * 8] = pa;
    const unsigned short* ks = (const unsigned short*)&k4;
    float ssq = 0.f;
    #pragma unroll
    for (int j = 0; j < 8; ++j) { float kv = bf2f(ks[j]); ssq += kv * kv; }
    atomicAdd(&rnF[t], ssq);
  }
  __syncthreads();

  // wave0: cumprod per channel d (fp32 regs, bf16 store) + Dvec/lendF; wave1: rn
  if (tid < 64) {
    int d = tid; float cum = 1.f;
    #pragma unroll
    for (int t = 0; t < 64; ++t) {
      cum *= bf2f(lamB[t * 64 + d]);
      lamB[t * 64 + d] = f2bf(cum);
    }
    Dvec[(long)bhc * 64 + d] = cum;
    lendF[d] = cum;
  } else if (tid < 128) {
    int t = tid - 64;
    rnF[t] = 1.f / fmaxf(sqrtf(rnF[t]), 1e-12f);
  }
  __syncthreads();

  // transform in place: q~ = q*lam; k~ = (k*rn[t])/lam
  #pragma unroll
  for (int j = 0; j < 16; ++j) {
    int e = j * 256 + tid;
    int t = e >> 6;                 // wave-uniform
    float lam = bf2f(lamB[e]);
    float kn = bf2f(Kb[e]) * rnF[t];
    Qb[e] = f2bf(bf2f(Qb[e]) * lam);
    Kb[e] = f2bf(kn / lam);
  }
  __syncthreads();

  // write qt
  {
    const long obase = (long)bhc * 4096;
    uint4* gq = (uint4*)(qt + obase);
    const uint4* lq = (const uint4*)Qb;
    gq[tid] = lq[tid]; gq[tid + 256] = lq[tid + 256];
  }

  const long base = (long)bhc * 4096;
  const int wave = tid >> 6, lane = tid & 63, quad = lane >> 4, l16 = lane & 15;
  const int mrow = wave * 16 + l16;
  unsigned short* Ps = lamB;   // lamB dead after transform

  // identity A-fragment for MFMA transpose: A[m][k] = (k == (wave&1)*16 + m)
  union { short8 v; short s[8]; } aI;
  aI.v = (short8){0,0,0,0,0,0,0,0};
  {
    int target = ((wave & 1) * 16 + l16) - quad * 8;
    if (target >= 0 && target < 8) aI.s[target] = (short)0x3F80;
  }
  const int bsel = (wave >> 1) * 32;   // which 32-channel half this wave selects

  // P = q~ k~^T, causal mask -> Ps (each wave uses only its own 16 rows later)
  {
    short8 a0 = *(const short8*)&Qb[mrow * 64 + quad * 8];
    short8 a1 = *(const short8*)&Qb[mrow * 64 + 32 + quad * 8];
    #pragma unroll
    for (int nt = 0; nt < 4; ++nt) {
      short8 b0 = *(const short8*)&Kb[(nt * 16 + l16) * 64 + quad * 8];
      short8 b1 = *(const short8*)&Kb[(nt * 16 + l16) * 64 + 32 + quad * 8];
      f32x4 acc = (f32x4){0.f, 0.f, 0.f, 0.f};
      acc = __builtin_amdgcn_mfma_f32_16x16x32_bf16(a0, b0, acc, 0, 0, 0);
      acc = __builtin_amdgcn_mfma_f32_16x16x32_bf16(a1, b1, acc, 0, 0, 0);
      #pragma unroll
      for (int r = 0; r < 4; ++r) {
        int t = wave * 16 + quad * 4 + r, u = nt * 16 + l16;
        Ps[t * 64 + u] = (u <= t) ? f2bf(acc[r]) : (unsigned short)0;
      }
    }
  }
  // MFMA transpose: Vt[i][t] = Vb[t][i], Kt[j][t] = Kb[t][j]
  // wave w produces rows w*16..w*16+15 via A = identity selecting channel w*16+m.
  #pragma unroll
  for (int nt = 0; nt < 4; ++nt) {
    short8 bv = *(const short8*)&Vb[(nt * 16 + l16) * 64 + bsel + quad * 8];
    short8 bk = *(const short8*)&Kb[(nt * 16 + l16) * 64 + bsel + quad * 8];
    f32x4 av = (f32x4){0.f, 0.f, 0.f, 0.f};
    f32x4 ak = (f32x4){0.f, 0.f, 0.f, 0.f};
    av = __builtin_amdgcn_mfma_f32_16x16x32_bf16(aI.v, bv, av, 0, 0, 0);
    ak = __builtin_amdgcn_mfma_f32_16x16x32_bf16(aI.v, bk, ak, 0, 0, 0);
    #pragma unroll
    for (int r = 0; r < 4; ++r) {
      int i = wave * 16 + quad * 4 + r, t = nt * 16 + l16;
      Vt[i * TS + t] = f2bf(av[r]);
      Kt[i * TS + t] = f2bf(ak[r]);
    }
  }
  __syncthreads();

  // O_intra = P V : A = Ps rows t (own wave), B = Vt rows i (k = u)
  {
    short8 a0 = *(const short8*)&Ps[mrow * 64 + quad * 8];
    short8 a1 = *(const short8*)&Ps[mrow * 64 + 32 + quad * 8];
    #pragma unroll
    for (int nt = 0; nt < 4; ++nt) {
      short8 b0 = *(const short8*)&Vt[(nt * 16 + l16) * TS + quad * 8];
      short8 b1 = *(const short8*)&Vt[(nt * 16 + l16) * TS + 32 + quad * 8];
      f32x4 acc = (f32x4){0.f, 0.f, 0.f, 0.f};
      acc = __builtin_amdgcn_mfma_f32_16x16x32_bf16(a0, b0, acc, 0, 0, 0);
      acc = __builtin_amdgcn_mfma_f32_16x16x32_bf16(a1, b1, acc, 0, 0, 0);
      #pragma unroll
      for (int r = 0; r < 4; ++r) {
        int t = wave * 16 + quad * 4 + r, i = nt * 16 + l16;
        Ointra[base + t * 64 + i] = f2bf(acc[r]);
      }
    }
  }
  // Tt[i][j] = lend[j] * sum_t V^T[i][t] K~^T[j][t] : A = Vt rows i, B = Kt rows j
  {
    short8 a0 = *(const short8*)&Vt[mrow * TS + quad * 8];
    short8 a1 = *(const short8*)&Vt[mrow * TS + 32 + quad * 8];
    #pragma unroll
    for (int nt = 0; nt < 4; ++nt) {
      short8 b0 = *(const short8*)&Kt[(nt * 16 + l16) * TS + quad * 8];
      short8 b1 = *(const short8*)&Kt[(nt * 16 + l16) * TS + 32 + quad * 8];
      f32x4 acc = (f32x4){0.f, 0.f, 0.f, 0.f};
      acc = __builtin_amdgcn_mfma_f32_16x16x32_bf16(a0, b0, acc, 0, 0, 0);
      acc = __builtin_amdgcn_mfma_f32_16x16x32_bf16(a1, b1, acc, 0, 0, 0);
      float le = lendF[nt * 16 + l16];
      #pragma unroll
      for (int r = 0; r < 4; ++r) {
        int i = wave * 16 + quad * 4 + r, j = nt * 16 + l16;
        Tt[base + i * 64 + j] = f2bf(acc[r] * le);
      }
    }
  }
}

// ---------------- K5: chunk-state scan, element-parallel ---------------------
__global__ __launch_bounds__(256) void scan_kernel(const unsigned short* __restrict__ Tt,
                                                   const float* __restrict__ Dvec,
                                                   unsigned short* __restrict__ Sst) {
  const int bh = blockIdx.x;
  const int e = blockIdx.y * 256 + threadIdx.x;
  const int j = e & 63;
  float S = 0.f;
  for (int c = 0; c < 64; ++c) {
    const long idx = ((long)(bh * 64 + c)) * 4096 + e;
    const float dj = Dvec[((long)(bh * 64 + c)) * 64 + j];
    Sst[idx] = f2bf(S);                 // state BEFORE chunk c
    S = dj * S + bf2f(Tt[idx]);
  }
}

// ---------------- K6: O = O_intra + q~ @ S_prev, pack to [tok][h*64+i] bf16 --
__global__ __launch_bounds__(256) void combine_kernel(const unsigned short* __restrict__ qt,
                                                      const unsigned short* __restrict__ Sst,
                                                      const unsigned short* __restrict__ Ointra,
                                                      unsigned short* __restrict__ O) {
  const int bhc = blockIdx.x;
  const int c = bhc & 63, bh = bhc >> 6;
  const int h = bh & 7, b = bh >> 3;
  const long base = (long)bhc * 4096;
  __shared__ __align__(16) unsigned short Qs[4096], Sb[4096];
  const int tid = threadIdx.x;
  {
    const uint4* gq = (const uint4*)(qt + base);  uint4* lq = (uint4*)Qs;
    const uint4* gs = (const uint4*)(Sst + base); uint4* ls = (uint4*)Sb;
    lq[tid] = gq[tid]; lq[tid + 256] = gq[tid + 256];
    ls[tid] = gs[tid]; ls[tid + 256] = gs[tid + 256];
  }
  __syncthreads();
  const int wave = tid >> 6, lane = tid & 63, quad = lane >> 4, l16 = lane & 15;
  const int mrow = wave * 16 + l16;
  short8 a0 = *(const short8*)&Qs[mrow * 64 + quad * 8];
  short8 a1 = *(const short8*)&Qs[mrow * 64 + 32 + quad * 8];
  #pragma unroll
  for (int nt = 0; nt < 4; ++nt) {
    f32x4 acc;
    #pragma unroll
    for (int r = 0; r < 4; ++r) {
      int t = wave * 16 + quad * 4 + r, i = nt * 16 + l16;
      acc[r] = bf2f(Ointra[base + t * 64 + i]);
    }
    short8 b0 = *(const short8*)&Sb[(nt * 16 + l16) * 64 + quad * 8];
    short8 b1 = *(const short8*)&Sb[(nt * 16 + l16) * 64 + 32 + quad * 8];
    acc = __builtin_amdgcn_mfma_f32_16x16x32_bf16(a0, b0, acc, 0, 0, 0);
    acc = __builtin_amdgcn_mfma_f32_16x16x32_bf16(a1, b1, acc, 0, 0, 0);
    #pragma unroll
    for (int r = 0; r < 4; ++r) {
      int t = wave * 16 + quad * 4 + r, i = nt * 16 + l16;
      O[((long)(b * 4096 + c * 64 + t)) * 512 + h * 64 + i] = f2bf(acc[r]);
    }
  }
}

// ---------------- host ----------------
// Workspace layout (KB offsets), total 153088 KB, lifetime-aliased:
//   0       Wt     4096 KB   (whole call)
//   4096    Wot    1024 KB
//   5120    Dvec   512 KB
//   5632    qt     16384 KB  (prep_intra -> combine)
//   22016   Ttb    16384 KB  (prep_intra -> scan)
//   38400   Sst    16384 KB  (scan -> combine)
//   54784   xn     32768 KB  (init -> gemm1); reused after gemm1:
//             Ointra @54784 (16384 KB), Ob @71168 (16384 KB)
//   87552   Cb     65536 KB  (gemm1 -> prep_intra)
extern "C" void kernel_launch(void* const* d_in, const int* in_sizes, int n_in,
                              void* d_out, int out_size, void* d_ws, size_t ws_size,
                              hipStream_t stream) {
  const float* x     = (const float*)d_in[0];
  const float* Wq    = (const float*)d_in[1];
  const float* Wk    = (const float*)d_in[2];
  const float* Wv    = (const float*)d_in[3];
  const float* Wa    = (const float*)d_in[4];
  const float* ba    = (const float*)d_in[5];
  const float* Wo    = (const float*)d_in[6];
  const float* gamma = (const float*)d_in[7];
  const float* beta  = (const float*)d_in[8];
  float* out = (float*)d_out;

  char* ws = (char*)d_ws;
  const size_t KB = 1024;
  unsigned short* Wt     = (unsigned short*)(ws + 0 * KB);
  unsigned short* Wot    = (unsigned short*)(ws + 4096 * KB);
  float*          Dvec   = (float*)         (ws + 5120 * KB);
  unsigned short* qt     = (unsigned short*)(ws + 5632 * KB);
  unsigned short* Ttb    = (unsigned short*)(ws + 22016 * KB);
  unsigned short* Sst    = (unsigned short*)(ws + 38400 * KB);
  unsigned short* xn     = (unsigned short*)(ws + 54784 * KB);
  unsigned short* Ointra = (unsigned short*)(ws + 54784 * KB);  // aliases xn (dead after gemm1)
  unsigned short* Ob     = (unsigned short*)(ws + 71168 * KB);  // aliases xn tail (dead)
  unsigned short* Cb     = (unsigned short*)(ws + 87552 * KB);

  init_kernel<<<NTOK + 2048 + 512, 256, 0, stream>>>(x, gamma, beta, Wq, Wk, Wv, Wa, Wo, xn, Wt, Wot);
  gemm_bt<0><<<dim3(NTOK / 256, 2048 / 128), 512, 0, stream>>>(xn, Wt, Cb, nullptr, nullptr, NTOK, 2048, 1024);
  prep_intra_kernel<<<NBHC, 256, 0, stream>>>(Cb, ba, qt, Dvec, Ointra, Ttb);
  scan_kernel<<<dim3(32, 16), 256, 0, stream>>>(Ttb, Dvec, Sst);
  combine_kernel<<<NBHC, 256, 0, stream>>>(qt, Sst, Ointra, Ob);
  gemm_bt<1><<<dim3(NTOK / 256, 1024 / 128), 512, 0, stream>>>(Ob, Wot, nullptr, out, x, NTOK, 1024, 512);
}